// Round 3
// baseline (343.970 us; speedup 1.0000x reference)
//
#include <hip/hip_runtime.h>
#include <math.h>

#define CDIM 8
#define CSZ  4096
#define NB   8
#define ND   1024
#define NT   4096
#define NFR  (NB * NT)               // 32768 frames
#define NSLICE 16
#define SLEN   (CSZ / NSLICE)        // 256 entries per slice
#define TAU  1.5e-4f                 // f32-vs-f64 sim safety gap (delta <= ~1e-5)

typedef float v2f __attribute__((ext_vector_type(2)));

// ---- d_out layout (flat f32, return order) ----
static constexpr size_t CL_OFF  = (size_t)NB * ND * NT;
static constexpr size_t CBL_OFF = CL_OFF + NB;
static constexpr size_t IDX_OFF = CBL_OFF + NB;
static constexpr size_t LAT_OFF = IDX_OFF + (size_t)NB * NT;

// ---- d_ws layout (byte offsets) ----
static constexpr size_t WT64_B   = 0;                              // f64[16384] w_in transposed
static constexpr size_t WT32_B   = 131072;                         // f32[16384]
static constexpr size_t CBN64A_B = 196608;                         // f64[4096*8]
static constexpr size_t CBN64B_B = 458752;                         // f64[4096*8]
static constexpr size_t CBN32A_B = 720896;                         // f32[4096*8]
static constexpr size_t CBN32B_B = 851968;                         // f32[4096*8]
static constexpr size_t ZA32_B   = 983040;                         // f32[NFR*16]
static constexpr size_t E32_B    = ZA32_B + 2097152;               // f32[NFR*16]
static constexpr size_t ZQT_B    = E32_B + 2097152;                // f32[16*NFR] transposed codewords
static constexpr size_t BV_B     = ZQT_B + 2097152;                // f64[NSLICE*NFR*4] packed best1/2
static constexpr size_t PART_B   = BV_B + (size_t)NSLICE * NFR * 4 * 8;  // f64[512]
static constexpr size_t WS_NEED  = PART_B + 512 * 8;               // ~24.06 MB

__device__ __forceinline__ double pack_sim(float splus2, int jc) {
    // positive-double bit trick: value order == (sim, -j) lexicographic order
    return __hiloint2double(__float_as_int(splus2), jc);
}

// ================= prep =================
__global__ void vq_prep(const float* __restrict__ w_in_a, const float* __restrict__ w_in_b,
                        const float* __restrict__ cb_a,  const float* __restrict__ cb_b,
                        double* __restrict__ wT64, float* __restrict__ wT32,
                        double* __restrict__ cbn64A, double* __restrict__ cbn64B,
                        float* __restrict__ cbn32A,  float* __restrict__ cbn32B) {
    int id = blockIdx.x * 256 + threadIdx.x;
    if (id < 16384) {
        int i = id >> 4, o = id & 15;
        float w = (o < 8) ? w_in_a[o * ND + i] : w_in_b[(o - 8) * ND + i];
        wT64[id] = (double)w;
        wT32[id] = w;
    } else if (id < 16384 + 2 * CSZ) {
        int e = id - 16384;
        int book = e >> 12, j = e & (CSZ - 1);
        const float* src = (book ? cb_b : cb_a) + (size_t)j * CDIM;
        double* d64 = (book ? cbn64B : cbn64A) + (size_t)j * CDIM;
        float*  d32 = (book ? cbn32B : cbn32A) + (size_t)j * CDIM;
        double c[CDIM]; double n2 = 0.0;
#pragma unroll
        for (int k = 0; k < CDIM; ++k) { c[k] = (double)src[k]; n2 = fma(c[k], c[k], n2); }
        double den = fmax(sqrt(n2), 1e-12);
#pragma unroll
        for (int k = 0; k < CDIM; ++k) { double v = c[k] / den; d64[k] = v; d32[k] = (float)v; }
    }
}

// ================= A: f32 projection + normalize, 512 blocks x 512 thr =================
__global__ void __launch_bounds__(512, 4)
vq_proj(const float* __restrict__ z,
        const float* __restrict__ b_in_a, const float* __restrict__ b_in_b,
        const float* __restrict__ wT32,
        float* __restrict__ za32, float* __restrict__ e32,
        float* __restrict__ out) {
    const int tid  = threadIdx.x;
    const int lane = tid & 63;
    const int wave = __builtin_amdgcn_readfirstlane(tid >> 6);  // 0..7
    const int blk  = blockIdx.x;
    const int b    = blk >> 6;
    const int t    = ((blk & 63) << 6) + lane;
    const int f    = (blk << 6) + lane;

    __shared__ float red[8][64][17];                            // 34.8 KB, stride-17: conflict-free

    float acc[16];
#pragma unroll
    for (int k = 0; k < 16; ++k) acc[k] = 0.0f;

    const float* zp = z + ((size_t)b * ND) * NT + t;
    const int i0 = wave * 128;
#pragma unroll 8
    for (int ii = 0; ii < 128; ++ii) {
        const int i = i0 + ii;
        const float zd = zp[(size_t)i * NT];
        const float* wr = wT32 + (size_t)i * 16;                // uniform -> s_load
#pragma unroll
        for (int k = 0; k < 16; ++k) acc[k] = fmaf(wr[k], zd, acc[k]);
    }
#pragma unroll
    for (int k = 0; k < 16; ++k) red[wave][lane][k] = acc[k];
    __syncthreads();

    if (wave != 0) return;

    float za16[16];
#pragma unroll
    for (int k = 0; k < 16; ++k) {
        float s = red[0][lane][k];
#pragma unroll
        for (int w = 1; w < 8; ++w) s += red[w][lane][k];
        za16[k] = s;
    }
#pragma unroll
    for (int k = 0; k < 8; ++k) { za16[k] += b_in_a[k]; za16[8 + k] += b_in_b[k]; }

    // latent output
#pragma unroll
    for (int k = 0; k < 16; ++k)
        out[LAT_OFF + ((size_t)b * 16 + k) * NT + t] = za16[k];

    // store za32 (for loss)
    float4* zs = (float4*)(za32 + (size_t)f * 16);
#pragma unroll
    for (int q = 0; q < 4; ++q)
        zs[q] = make_float4(za16[4*q], za16[4*q+1], za16[4*q+2], za16[4*q+3]);

    // normalize f32 -> e32
    float n2a = 0.f, n2b = 0.f;
#pragma unroll
    for (int k = 0; k < 8; ++k) { n2a = fmaf(za16[k], za16[k], n2a); n2b = fmaf(za16[8+k], za16[8+k], n2b); }
    const float ia_ = 1.0f / fmaxf(sqrtf(n2a), 1e-12f);
    const float ib_ = 1.0f / fmaxf(sqrtf(n2b), 1e-12f);
    float e[16];
#pragma unroll
    for (int k = 0; k < 8; ++k) { e[k] = za16[k] * ia_; e[8 + k] = za16[8 + k] * ib_; }
    float4* es = (float4*)(e32 + (size_t)f * 16);
#pragma unroll
    for (int q = 0; q < 4; ++q)
        es[q] = make_float4(e[4*q], e[4*q+1], e[4*q+2], e[4*q+3]);
}

// ================= B: f32 prescan, packed best1/best2; 2048 blocks x 256 thr =================
__global__ void __launch_bounds__(256, 6)
vq_scan(const float* __restrict__ e32,
        const float* __restrict__ cbn32A, const float* __restrict__ cbn32B,
        double* __restrict__ bv) {
    const int tid   = threadIdx.x;
    const int lane  = tid & 63;
    const int wave  = __builtin_amdgcn_readfirstlane(tid >> 6);
    const int fg    = blockIdx.x >> 2;
    const int slice = ((blockIdx.x & 3) << 2) | wave;            // 0..15
    const int f     = (fg << 6) + lane;
    const int j0    = slice * SLEN;

    const v2f* ep = (const v2f*)(e32 + (size_t)f * 16);
    v2f ea2[4], eb2[4];
#pragma unroll
    for (int k = 0; k < 4; ++k) { ea2[k] = ep[k]; eb2[k] = ep[4 + k]; }

    double b1a = 0.0, b2a = 0.0, b1b = 0.0, b2b = 0.0;

#pragma unroll 4
    for (int jj = 0; jj < SLEN; ++jj) {
        const int j = j0 + jj;
        const v2f* ca = (const v2f*)(cbn32A + (size_t)j * 8);    // uniform -> s_load
        const v2f* cb = (const v2f*)(cbn32B + (size_t)j * 8);
        v2f aA = {1.0f, 1.0f};                                   // horizontal add -> +2 shift
        v2f aB = {1.0f, 1.0f};
#pragma unroll
        for (int k = 0; k < 4; ++k) { aA = ea2[k] * ca[k] + aA; aB = eb2[k] * cb[k] + aB; }
        const float sA = aA.x + aA.y;
        const float sB = aB.x + aB.y;
        const int jc = 4095 - j;
        const double vA = pack_sim(sA, jc);
        const double vB = pack_sim(sB, jc);
        b2a = fmax(b2a, fmin(vA, b1a)); b1a = fmax(b1a, vA);
        b2b = fmax(b2b, fmin(vB, b1b)); b1b = fmax(b1b, vB);
    }

    double* bp = bv + ((size_t)slice * NFR + f) * 4;
    bp[0] = b1a; bp[1] = b2a; bp[2] = b1b; bp[3] = b2b;
}

// ================= C: combine + gated f64 rescue + gather; 512 blocks x 64 thr =================
__global__ void __launch_bounds__(64)
vq_sel(const double* __restrict__ bv,
       const float* __restrict__ za32, const float* __restrict__ z,
       const double* __restrict__ wT64,
       const float* __restrict__ b_in_a, const float* __restrict__ b_in_b,
       const double* __restrict__ cbn64A, const double* __restrict__ cbn64B,
       const float* __restrict__ cb_a, const float* __restrict__ cb_b,
       float* __restrict__ zqT, float* __restrict__ out, double* __restrict__ part) {
    const int lane = threadIdx.x;
    const int fg   = blockIdx.x;
    const int b    = fg >> 6;
    const int f    = (fg << 6) + lane;

    double B1a = 0.0, B2a = 0.0, B1b = 0.0, B2b = 0.0;
#pragma unroll
    for (int s = 0; s < NSLICE; ++s) {
        const double* bp = bv + ((size_t)s * NFR + f) * 4;
        const double v1 = bp[0], v2 = bp[1], w1 = bp[2], w2 = bp[3];
        B2a = fmax(B2a, fmin(v1, B1a)); B1a = fmax(B1a, v1); B2a = fmax(B2a, v2);
        B2b = fmax(B2b, fmin(w1, B1b)); B1b = fmax(B1b, w1); B2b = fmax(B2b, w2);
    }
    unsigned long long ua = (unsigned long long)__double_as_longlong(B1a);
    unsigned long long ub = (unsigned long long)__double_as_longlong(B1b);
    int iA = 4095 - (int)(ua & 0xFFFull);
    int iB = 4095 - (int)(ub & 0xFFFull);
    const float s1a = __uint_as_float((unsigned)(ua >> 32));
    const float s1b = __uint_as_float((unsigned)(ub >> 32));
    const float s2a = __uint_as_float((unsigned)((unsigned long long)__double_as_longlong(B2a) >> 32));
    const float s2b = __uint_as_float((unsigned)((unsigned long long)__double_as_longlong(B2b) >> 32));

    const bool needy = ((s1a - s2a) < TAU) || ((s1b - s2b) < TAU);
    unsigned long long m = __ballot(needy);
    while (m) {
        const int src = __ffsll((long long)m) - 1; m &= (m - 1);
        const int tb = ((fg & 63) << 6) + src;
        // exact f64 projection for this frame, wave-cooperative (lane = channel group)
        double acc[16];
#pragma unroll
        for (int k = 0; k < 16; ++k) acc[k] = 0.0;
        const float* zc = z + ((size_t)b * ND) * NT + tb;
#pragma unroll 2
        for (int r = 0; r < 16; ++r) {
            const int c = (r << 6) + lane;
            const double zd = (double)zc[(size_t)c * NT];
            const double* wr = wT64 + (size_t)c * 16;
#pragma unroll
            for (int k = 0; k < 16; ++k) acc[k] = fma(wr[k], zd, acc[k]);
        }
#pragma unroll
        for (int off = 32; off > 0; off >>= 1) {
#pragma unroll
            for (int k = 0; k < 16; ++k) acc[k] += __shfl_xor(acc[k], off);
        }
#pragma unroll
        for (int k = 0; k < 8; ++k) { acc[k] += (double)b_in_a[k]; acc[8 + k] += (double)b_in_b[k]; }

        double n2a = 0.0, n2b = 0.0;
#pragma unroll
        for (int k = 0; k < 8; ++k) { n2a = fma(acc[k], acc[k], n2a); n2b = fma(acc[8+k], acc[8+k], n2b); }
        const double ja_ = 1.0 / fmax(sqrt(n2a), 1e-12);
        const double jb_ = 1.0 / fmax(sqrt(n2b), 1e-12);
        double ea64[8], eb64[8];
#pragma unroll
        for (int k = 0; k < 8; ++k) { ea64[k] = acc[k] * ja_; eb64[k] = acc[8 + k] * jb_; }

        double bva = -1e300, bvb = -1e300; int ba = 0, bb2 = 0;
        for (int e = lane; e < CSZ; e += 64) {
            const double* ra = cbn64A + (size_t)e * 8;
            const double* rb = cbn64B + (size_t)e * 8;
            double sA = 0.0, sB = 0.0;
#pragma unroll
            for (int k = 0; k < 8; ++k) { sA = fma(ea64[k], ra[k], sA); sB = fma(eb64[k], rb[k], sB); }
            if (sA > bva) { bva = sA; ba = e; }
            if (sB > bvb) { bvb = sB; bb2 = e; }
        }
#pragma unroll
        for (int off = 32; off > 0; off >>= 1) {
            double ov = __shfl_xor(bva, off); int oi = __shfl_xor(ba, off);
            if (ov > bva || (ov == bva && oi < ba)) { bva = ov; ba = oi; }
            ov = __shfl_xor(bvb, off); oi = __shfl_xor(bb2, off);
            if (ov > bvb || (ov == bvb && oi < bb2)) { bvb = ov; bb2 = oi; }
        }
        if (lane == src) { iA = ba; iB = bb2; }
    }

    // gather raw codewords, write transposed zqT + idx + loss partial
    const float4 qa0 = *(const float4*)(cb_a + (size_t)iA * CDIM);
    const float4 qa1 = *(const float4*)(cb_a + (size_t)iA * CDIM + 4);
    const float4 qb0 = *(const float4*)(cb_b + (size_t)iB * CDIM);
    const float4 qb1 = *(const float4*)(cb_b + (size_t)iB * CDIM + 4);
    const float zaq[8] = {qa0.x, qa0.y, qa0.z, qa0.w, qa1.x, qa1.y, qa1.z, qa1.w};
    const float zbq[8] = {qb0.x, qb0.y, qb0.z, qb0.w, qb1.x, qb1.y, qb1.z, qb1.w};

    out[IDX_OFF + (size_t)f] = (float)(iA * CSZ + iB);
#pragma unroll
    for (int k = 0; k < 8; ++k) {
        zqT[(size_t)k * NFR + f]       = zaq[k];
        zqT[(size_t)(8 + k) * NFR + f] = zbq[k];
    }

    const float* zap = za32 + (size_t)f * 16;
    double s = 0.0;
#pragma unroll
    for (int k = 0; k < 8; ++k) {
        const double d0 = (double)zap[k]     - (double)zaq[k]; s = fma(d0, d0, s);
        const double d1 = (double)zap[8 + k] - (double)zbq[k]; s = fma(d1, d1, s);
    }
#pragma unroll
    for (int off = 32; off > 0; off >>= 1) s += __shfl_down(s, off);
    if (lane == 0) part[fg] = s;
}

// ================= D: streaming out-projection; 2048 blocks x 256 thr =================
__global__ void __launch_bounds__(256, 4)
vq_store(const float* __restrict__ zqT,
         const float* __restrict__ w_out_a, const float* __restrict__ b_out_a,
         const float* __restrict__ w_out_b, const float* __restrict__ b_out_b,
         float* __restrict__ out) {
    const int tid  = threadIdx.x;
    const int lane = tid & 63;
    const int wave = __builtin_amdgcn_readfirstlane(tid >> 6);   // 0..3
    const int blk  = blockIdx.x;
    const int b    = blk >> 8;
    const int rem  = blk & 255;
    const int tt   = rem >> 4;                                   // 16 t-tiles of 256
    const int ct   = rem & 15;                                   // 16 c-tiles of 64
    const int t0   = (tt << 8) + (lane << 2);
    const size_t f0 = ((size_t)b << 12) + t0;

    const bool bookb = (ct >= 8);
    const float* wO = bookb ? w_out_b : w_out_a;
    const float* bO = bookb ? b_out_b : b_out_a;
    const int kb = bookb ? 8 : 0;

    float4 q[8];
#pragma unroll
    for (int k = 0; k < 8; ++k)
        q[k] = *(const float4*)(zqT + (size_t)(kb + k) * NFR + f0);

    const int cl0 = ((ct & 7) << 6) + (wave << 4);               // local channel in half
#pragma unroll 4
    for (int cc = 0; cc < 16; ++cc) {
        const int cl = cl0 + cc;
        const float* wr = wO + (size_t)cl * 8;                   // uniform -> s_load
        const float bias = bO[cl];
        float4 o = make_float4(bias, bias, bias, bias);
#pragma unroll
        for (int k = 0; k < 8; ++k) {
            o.x = fmaf(wr[k], q[k].x, o.x);
            o.y = fmaf(wr[k], q[k].y, o.y);
            o.z = fmaf(wr[k], q[k].z, o.z);
            o.w = fmaf(wr[k], q[k].w, o.w);
        }
        const int c = (bookb ? 512 : 0) + cl;
        *(float4*)(out + ((size_t)b * ND + c) * NT + t0) = o;
    }
}

__global__ void vq_finalize(const double* __restrict__ part, float* __restrict__ out) {
    const int b = threadIdx.x;
    if (b < NB) {
        double s = 0.0;
        for (int j = 0; j < 64; ++j) s += part[(size_t)b * 64 + j];
        const float v = (float)(s * (1.0 / 32768.0));
        out[CL_OFF + b]  = v;
        out[CBL_OFF + b] = v;
    }
}

// ================= fallback monolith (round-1 proven, if ws too small) =================
__global__ void __launch_bounds__(256, 2)
vq_mono(const float* __restrict__ z,
        const float* __restrict__ w_in_a, const float* __restrict__ b_in_a,
        const float* __restrict__ w_in_b, const float* __restrict__ b_in_b,
        const float* __restrict__ w_out_a, const float* __restrict__ b_out_a,
        const float* __restrict__ w_out_b, const float* __restrict__ b_out_b,
        const float* __restrict__ cb_a, const float* __restrict__ cb_b,
        float* __restrict__ out, double* __restrict__ part) {
    const int tid  = threadIdx.x;
    const int lane = tid & 63;
    const int wave = __builtin_amdgcn_readfirstlane(tid >> 6);
    const int blk  = blockIdx.x;
    const int b    = blk >> 6;
    const int t    = ((blk & 63) << 6) + lane;

    __shared__ double red[4][64][9];
    __shared__ double sBest[2][4][64];
    __shared__ int    sIdx[2][4][64];

    double acc[16];
#pragma unroll
    for (int k = 0; k < 16; ++k) acc[k] = 0.0;
    const float* zp = z + ((size_t)b * ND) * NT + t;
    const int i0 = wave * 256;
#pragma unroll 2
    for (int ii = 0; ii < 256; ++ii) {
        const int i = i0 + ii;
        const double zd = (double)zp[(size_t)i * NT];
#pragma unroll
        for (int o = 0; o < 8; ++o) {
            acc[o]     = fma((double)w_in_a[o * ND + i], zd, acc[o]);
            acc[8 + o] = fma((double)w_in_b[o * ND + i], zd, acc[8 + o]);
        }
    }
    double za[16];
#pragma unroll
    for (int r = 0; r < 2; ++r) {
#pragma unroll
        for (int k = 0; k < 8; ++k) red[wave][lane][k] = acc[8 * r + k];
        __syncthreads();
#pragma unroll
        for (int k = 0; k < 8; ++k)
            za[8*r+k] = ((red[0][lane][k] + red[1][lane][k]) + red[2][lane][k]) + red[3][lane][k];
        __syncthreads();
    }
#pragma unroll
    for (int k = 0; k < 8; ++k) { za[k] += (double)b_in_a[k]; za[8 + k] += (double)b_in_b[k]; }

    if (wave == 0) {
#pragma unroll
        for (int k = 0; k < 16; ++k)
            out[LAT_OFF + ((size_t)b * 16 + k) * NT + t] = (float)za[k];
    }

    double ea[8], eb[8];
    {
        double n2 = 0.0;
#pragma unroll
        for (int k = 0; k < 8; ++k) n2 = fma(za[k], za[k], n2);
        double inv = 1.0 / fmax(sqrt(n2), 1e-12);
#pragma unroll
        for (int k = 0; k < 8; ++k) ea[k] = za[k] * inv;
    }
    {
        double n2 = 0.0;
#pragma unroll
        for (int k = 0; k < 8; ++k) n2 = fma(za[8 + k], za[8 + k], n2);
        double inv = 1.0 / fmax(sqrt(n2), 1e-12);
#pragma unroll
        for (int k = 0; k < 8; ++k) eb[k] = za[8 + k] * inv;
    }

    double bestA = -1e300, bestB = -1e300;
    int ibA = 0, ibB = 0;
    const int j0 = wave << 10;
    for (int jj = 0; jj < 1024; ++jj) {
        const int j = j0 + jj;
        const float* ra = cb_a + (size_t)j * CDIM;
        const float* rb = cb_b + (size_t)j * CDIM;
        double na = 0.0, nb = 0.0, sA = 0.0, sB = 0.0;
#pragma unroll
        for (int k = 0; k < 8; ++k) {
            double av = (double)ra[k], bv2 = (double)rb[k];
            na = fma(av, av, na); nb = fma(bv2, bv2, nb);
            sA = fma(ea[k], av, sA); sB = fma(eb[k], bv2, sB);
        }
        sA /= fmax(sqrt(na), 1e-12);
        sB /= fmax(sqrt(nb), 1e-12);
        if (sA > bestA) { bestA = sA; ibA = j; }
        if (sB > bestB) { bestB = sB; ibB = j; }
    }
    sBest[0][wave][lane] = bestA; sIdx[0][wave][lane] = ibA;
    sBest[1][wave][lane] = bestB; sIdx[1][wave][lane] = ibB;
    __syncthreads();

    double bA = sBest[0][0][lane]; int iA = sIdx[0][0][lane];
    double bB = sBest[1][0][lane]; int iB = sIdx[1][0][lane];
#pragma unroll
    for (int w2 = 1; w2 < 4; ++w2) {
        double d = sBest[0][w2][lane]; int j2 = sIdx[0][w2][lane];
        if (d > bA) { bA = d; iA = j2; }
        d = sBest[1][w2][lane]; j2 = sIdx[1][w2][lane];
        if (d > bB) { bB = d; iB = j2; }
    }

    float4 qa0 = *(const float4*)(cb_a + (size_t)iA * CDIM);
    float4 qa1 = *(const float4*)(cb_a + (size_t)iA * CDIM + 4);
    float4 qb0 = *(const float4*)(cb_b + (size_t)iB * CDIM);
    float4 qb1 = *(const float4*)(cb_b + (size_t)iB * CDIM + 4);
    float zaq[8] = {qa0.x, qa0.y, qa0.z, qa0.w, qa1.x, qa1.y, qa1.z, qa1.w};
    float zbq[8] = {qb0.x, qb0.y, qb0.z, qb0.w, qb1.x, qb1.y, qb1.z, qb1.w};

    if (wave == 0) {
        out[IDX_OFF + (size_t)b * NT + t] = (float)(iA * CSZ + iB);
        double s = 0.0;
#pragma unroll
        for (int k = 0; k < 8; ++k) {
            double d0 = za[k]     - (double)zaq[k]; s = fma(d0, d0, s);
            double d1 = za[8 + k] - (double)zbq[k]; s = fma(d1, d1, s);
        }
#pragma unroll
        for (int off = 32; off > 0; off >>= 1) s += __shfl_down(s, off);
        if (lane == 0) part[blk] = s;
    }

    const int c0 = wave << 7;
    const size_t obase = ((size_t)b * ND) * NT + t;
    for (int cc = 0; cc < 128; ++cc) {
        const int c = c0 + cc;
        const float* wa = w_out_a + (size_t)c * CDIM;
        const float* wb = w_out_b + (size_t)c * CDIM;
        float sa = b_out_a[c], sb = b_out_b[c];
#pragma unroll
        for (int k = 0; k < 8; ++k) { sa = fmaf(wa[k], zaq[k], sa); sb = fmaf(wb[k], zbq[k], sb); }
        out[obase + (size_t)c * NT]         = sa;
        out[obase + (size_t)(512 + c) * NT] = sb;
    }
}

extern "C" void kernel_launch(void* const* d_in, const int* in_sizes, int n_in,
                              void* d_out, int out_size, void* d_ws, size_t ws_size,
                              hipStream_t stream) {
    const float* z       = (const float*)d_in[0];
    const float* w_in_a  = (const float*)d_in[1];
    const float* b_in_a  = (const float*)d_in[2];
    const float* w_in_b  = (const float*)d_in[3];
    const float* b_in_b  = (const float*)d_in[4];
    const float* w_out_a = (const float*)d_in[5];
    const float* b_out_a = (const float*)d_in[6];
    const float* w_out_b = (const float*)d_in[7];
    const float* b_out_b = (const float*)d_in[8];
    const float* cb_a    = (const float*)d_in[9];
    const float* cb_b    = (const float*)d_in[10];
    float* out = (float*)d_out;
    char* ws = (char*)d_ws;

    if (ws_size >= WS_NEED) {
        double* wT64   = (double*)(ws + WT64_B);
        float*  wT32   = (float*) (ws + WT32_B);
        double* cbn64A = (double*)(ws + CBN64A_B);
        double* cbn64B = (double*)(ws + CBN64B_B);
        float*  cbn32A = (float*) (ws + CBN32A_B);
        float*  cbn32B = (float*) (ws + CBN32B_B);
        float*  za32   = (float*) (ws + ZA32_B);
        float*  e32    = (float*) (ws + E32_B);
        float*  zqT    = (float*) (ws + ZQT_B);
        double* bv     = (double*)(ws + BV_B);
        double* part   = (double*)(ws + PART_B);

        vq_prep<<<96, 256, 0, stream>>>(w_in_a, w_in_b, cb_a, cb_b,
                                        wT64, wT32, cbn64A, cbn64B, cbn32A, cbn32B);
        vq_proj<<<512, 512, 0, stream>>>(z, b_in_a, b_in_b, wT32, za32, e32, out);
        vq_scan<<<2048, 256, 0, stream>>>(e32, cbn32A, cbn32B, bv);
        vq_sel<<<512, 64, 0, stream>>>(bv, za32, z, wT64, b_in_a, b_in_b,
                                       cbn64A, cbn64B, cb_a, cb_b, zqT, out, part);
        vq_store<<<2048, 256, 0, stream>>>(zqT, w_out_a, b_out_a, w_out_b, b_out_b, out);
        vq_finalize<<<1, 64, 0, stream>>>(part, out);
    } else {
        double* part = (double*)ws;
        vq_mono<<<512, 256, 0, stream>>>(z, w_in_a, b_in_a, w_in_b, b_in_b,
                                         w_out_a, b_out_a, w_out_b, b_out_b,
                                         cb_a, cb_b, out, part);
        vq_finalize<<<1, 64, 0, stream>>>(part, out);
    }
}

// Round 4
// 234.477 us; speedup vs baseline: 1.4670x; 1.4670x over previous
//
#include <hip/hip_runtime.h>
#include <math.h>

#define CDIM 8
#define CSZ  4096
#define NB   8
#define ND   1024
#define NT   4096
#define NFR  (NB * NT)               // 32768 frames
#define NSLICE 16
#define SLEN   (CSZ / NSLICE)        // 256 entries per slice
#define TAU  6e-5f                   // f32-vs-f64 sim safety gap (delta <= ~1.2e-6, 50x margin)

typedef float v2f __attribute__((ext_vector_type(2)));

// ---- d_out layout (flat f32, return order) ----
static constexpr size_t CL_OFF  = (size_t)NB * ND * NT;
static constexpr size_t CBL_OFF = CL_OFF + NB;
static constexpr size_t IDX_OFF = CBL_OFF + NB;
static constexpr size_t LAT_OFF = IDX_OFF + (size_t)NB * NT;

// ---- d_ws layout (byte offsets) ----
static constexpr size_t WT64_B   = 0;                         // f64[16384] w_in transposed [i][16]
static constexpr size_t CBN64A_B = 131072;                    // f64[4096*8]
static constexpr size_t CBN64B_B = 393216;                    // f64[4096*8]
static constexpr size_t CBN32A_B = 655360;                    // f32[4096*8]
static constexpr size_t CBN32B_B = 786432;                    // f32[4096*8]
static constexpr size_t ZA64_B   = 917504;                    // f64[NFR*16]
static constexpr size_t E32_B    = ZA64_B + (size_t)NFR*16*8; // f32[NFR*16]
static constexpr size_t BV_B     = E32_B + (size_t)NFR*16*4;  // f64[NSLICE*NFR*4]
static constexpr size_t IDXW_B   = BV_B + (size_t)NSLICE*NFR*4*8; // i32[NFR] packed (iA<<12)|iB
static constexpr size_t LIST_B   = IDXW_B + (size_t)NFR*4;    // i32[NFR] needy list
static constexpr size_t CNT_B    = LIST_B + (size_t)NFR*4;    // i32 counter (+pad)
static constexpr size_t PART_B   = CNT_B + 64;                // f64[128] loss partials
static constexpr size_t WS_NEED  = PART_B + 128*8;            // ~24.25 MB

__device__ __forceinline__ double pack_sim(float splus2, int jc) {
    // positive-double bit trick: value order == (sim, -j) lexicographic order
    return __hiloint2double(__float_as_int(splus2), jc);
}

// ================= prep: transposed f64 weights + normalized codebooks + cnt=0 =================
__global__ void vq_prep(const float* __restrict__ w_in_a, const float* __restrict__ w_in_b,
                        const float* __restrict__ cb_a,  const float* __restrict__ cb_b,
                        double* __restrict__ wT64,
                        double* __restrict__ cbn64A, double* __restrict__ cbn64B,
                        float* __restrict__ cbn32A,  float* __restrict__ cbn32B,
                        int* __restrict__ cnt) {
    int id = blockIdx.x * 256 + threadIdx.x;
    if (id == 0) *cnt = 0;
    if (id < 16384) {
        int i = id >> 4, o = id & 15;
        float w = (o < 8) ? w_in_a[o * ND + i] : w_in_b[(o - 8) * ND + i];
        wT64[id] = (double)w;
    } else if (id < 16384 + 2 * CSZ) {
        int e = id - 16384;
        int book = e >> 12, j = e & (CSZ - 1);
        const float* src = (book ? cb_b : cb_a) + (size_t)j * CDIM;
        double* d64 = (book ? cbn64B : cbn64A) + (size_t)j * CDIM;
        float*  d32 = (book ? cbn32B : cbn32A) + (size_t)j * CDIM;
        double c[CDIM]; double n2 = 0.0;
#pragma unroll
        for (int k = 0; k < CDIM; ++k) { c[k] = (double)src[k]; n2 = fma(c[k], c[k], n2); }
        double den = fmax(sqrt(n2), 1e-12);
#pragma unroll
        for (int k = 0; k < CDIM; ++k) { double v = c[k] / den; d64[k] = v; d32[k] = (float)v; }
    }
}

// ================= A: f64 projection + normalize; 512 blocks x 512 thr =================
__global__ void __launch_bounds__(512, 4)
vq_proj(const float* __restrict__ z,
        const float* __restrict__ b_in_a, const float* __restrict__ b_in_b,
        const double* __restrict__ wT64,
        double* __restrict__ za64, float* __restrict__ e32,
        float* __restrict__ out) {
    const int tid  = threadIdx.x;
    const int lane = tid & 63;
    const int wave = __builtin_amdgcn_readfirstlane(tid >> 6);  // 0..7
    const int blk  = blockIdx.x;
    const int b    = blk >> 6;
    const int t    = ((blk & 63) << 6) + lane;
    const int f    = (blk << 6) + lane;

    __shared__ double red[8][64][9];                            // 36.9 KB, two-round reduce

    double acc[16];
#pragma unroll
    for (int k = 0; k < 16; ++k) acc[k] = 0.0;

    const float* zp = z + ((size_t)b * ND) * NT + t;
    const int i0 = wave * 128;
#pragma unroll 4
    for (int ii = 0; ii < 128; ++ii) {
        const int i = i0 + ii;
        const double zd = (double)zp[(size_t)i * NT];
        const double* wr = wT64 + (size_t)i * 16;               // uniform -> s_load
#pragma unroll
        for (int k = 0; k < 16; ++k) acc[k] = fma(wr[k], zd, acc[k]);
    }

    double za16[16];
#pragma unroll
    for (int r = 0; r < 2; ++r) {
#pragma unroll
        for (int k = 0; k < 8; ++k) red[wave][lane][k] = acc[8 * r + k];
        __syncthreads();
        if (wave == 0) {
#pragma unroll
            for (int k = 0; k < 8; ++k) {
                double s = red[0][lane][k];
#pragma unroll
                for (int w = 1; w < 8; ++w) s += red[w][lane][k];
                za16[8 * r + k] = s;
            }
        }
        __syncthreads();
    }
    if (wave != 0) return;

#pragma unroll
    for (int k = 0; k < 8; ++k) { za16[k] += (double)b_in_a[k]; za16[8 + k] += (double)b_in_b[k]; }

    // latent output (f32)
#pragma unroll
    for (int k = 0; k < 16; ++k)
        out[LAT_OFF + ((size_t)b * 16 + k) * NT + t] = (float)za16[k];

    // store za64
    double* zf = za64 + (size_t)f * 16;
#pragma unroll
    for (int k = 0; k < 16; ++k) zf[k] = za16[k];

    // normalize in f64, store e32 (f32)
    double n2a = 0.0, n2b = 0.0;
#pragma unroll
    for (int k = 0; k < 8; ++k) { n2a = fma(za16[k], za16[k], n2a); n2b = fma(za16[8+k], za16[8+k], n2b); }
    const double ia_ = 1.0 / fmax(sqrt(n2a), 1e-12);
    const double ib_ = 1.0 / fmax(sqrt(n2b), 1e-12);
    float e[16];
#pragma unroll
    for (int k = 0; k < 8; ++k) { e[k] = (float)(za16[k] * ia_); e[8 + k] = (float)(za16[8 + k] * ib_); }
    float4* es = (float4*)(e32 + (size_t)f * 16);
#pragma unroll
    for (int q = 0; q < 4; ++q)
        es[q] = make_float4(e[4*q], e[4*q+1], e[4*q+2], e[4*q+3]);
}

// ================= B: f32 prescan, packed best1/best2; 2048 blocks x 256 thr =================
__global__ void __launch_bounds__(256, 6)
vq_scan(const float* __restrict__ e32,
        const float* __restrict__ cbn32A, const float* __restrict__ cbn32B,
        double* __restrict__ bv) {
    const int tid   = threadIdx.x;
    const int lane  = tid & 63;
    const int wave  = __builtin_amdgcn_readfirstlane(tid >> 6);
    const int fg    = blockIdx.x >> 2;
    const int slice = ((blockIdx.x & 3) << 2) | wave;            // 0..15
    const int f     = (fg << 6) + lane;
    const int j0    = slice * SLEN;

    const v2f* ep = (const v2f*)(e32 + (size_t)f * 16);
    v2f ea2[4], eb2[4];
#pragma unroll
    for (int k = 0; k < 4; ++k) { ea2[k] = ep[k]; eb2[k] = ep[4 + k]; }

    double b1a = 0.0, b2a = 0.0, b1b = 0.0, b2b = 0.0;

#pragma unroll 4
    for (int jj = 0; jj < SLEN; ++jj) {
        const int j = j0 + jj;
        const v2f* ca = (const v2f*)(cbn32A + (size_t)j * 8);    // uniform -> s_load
        const v2f* cb = (const v2f*)(cbn32B + (size_t)j * 8);
        v2f aA = {1.0f, 1.0f};                                   // +2 shift folded into init
        v2f aB = {1.0f, 1.0f};
#pragma unroll
        for (int k = 0; k < 4; ++k) { aA = ea2[k] * ca[k] + aA; aB = eb2[k] * cb[k] + aB; }
        const float sA = aA.x + aA.y;
        const float sB = aB.x + aB.y;
        const int jc = 4095 - j;
        const double vA = pack_sim(sA, jc);
        const double vB = pack_sim(sB, jc);
        b2a = fmax(b2a, fmin(vA, b1a)); b1a = fmax(b1a, vA);
        b2b = fmax(b2b, fmin(vB, b1b)); b1b = fmax(b1b, vB);
    }

    double* bp = bv + ((size_t)slice * NFR + f) * 4;
    bp[0] = b1a; bp[1] = b2a; bp[2] = b1b; bp[3] = b2b;
}

// ================= C: thread-per-frame combine + needy-list build; 128 blocks x 256 =================
__global__ void __launch_bounds__(256, 4)
vq_sel(const double* __restrict__ bv, int* __restrict__ idxAB,
       int* __restrict__ list, int* __restrict__ cnt) {
    const int f = blockIdx.x * 256 + threadIdx.x;

    double B1a = 0.0, B2a = 0.0, B1b = 0.0, B2b = 0.0;
#pragma unroll
    for (int s = 0; s < NSLICE; ++s) {
        const double* bp = bv + ((size_t)s * NFR + f) * 4;
        const double v1 = bp[0], v2 = bp[1], w1 = bp[2], w2 = bp[3];
        B2a = fmax(B2a, fmin(v1, B1a)); B1a = fmax(B1a, v1); B2a = fmax(B2a, v2);
        B2b = fmax(B2b, fmin(w1, B1b)); B1b = fmax(B1b, w1); B2b = fmax(B2b, w2);
    }
    const unsigned long long ua = (unsigned long long)__double_as_longlong(B1a);
    const unsigned long long ub = (unsigned long long)__double_as_longlong(B1b);
    const int iA = 4095 - (int)(ua & 0xFFFull);
    const int iB = 4095 - (int)(ub & 0xFFFull);
    const float s1a = __uint_as_float((unsigned)(ua >> 32));
    const float s1b = __uint_as_float((unsigned)(ub >> 32));
    const float s2a = __uint_as_float((unsigned)((unsigned long long)__double_as_longlong(B2a) >> 32));
    const float s2b = __uint_as_float((unsigned)((unsigned long long)__double_as_longlong(B2b) >> 32));

    idxAB[f] = (iA << 12) | iB;

    const bool needy = ((s1a - s2a) < TAU) || ((s1b - s2b) < TAU);
    if (needy) {
        const int p = atomicAdd(cnt, 1);
        list[p] = f;
    }
}

// ================= D: exact f64 rescue, one wave per needy frame; 1024 blocks x 64 =================
__global__ void __launch_bounds__(64, 2)
vq_rescue(const int* __restrict__ list, const int* __restrict__ cnt,
          const double* __restrict__ za64,
          const double* __restrict__ cbn64A, const double* __restrict__ cbn64B,
          int* __restrict__ idxAB) {
    const int lane = threadIdx.x;
    const int n = *cnt;
    for (int it = blockIdx.x; it < n; it += gridDim.x) {
        const int fr = list[it];
        const double* zr = za64 + (size_t)fr * 16;               // uniform -> s_load
        double zra[16];
#pragma unroll
        for (int k = 0; k < 16; ++k) zra[k] = zr[k];
        double n2a = 0.0, n2b = 0.0;
#pragma unroll
        for (int k = 0; k < 8; ++k) { n2a = fma(zra[k], zra[k], n2a); n2b = fma(zra[8+k], zra[8+k], n2b); }
        const double ja_ = 1.0 / fmax(sqrt(n2a), 1e-12);
        const double jb_ = 1.0 / fmax(sqrt(n2b), 1e-12);
        double ea64[8], eb64[8];
#pragma unroll
        for (int k = 0; k < 8; ++k) { ea64[k] = zra[k] * ja_; eb64[k] = zra[8 + k] * jb_; }

        double bva = -1e300, bvb = -1e300; int ba = 0, bb = 0;
        for (int e = lane; e < CSZ; e += 64) {                   // lane-strided: coalesced
            const double* ra = cbn64A + (size_t)e * 8;
            const double* rb = cbn64B + (size_t)e * 8;
            double sA = 0.0, sB = 0.0;
#pragma unroll
            for (int k = 0; k < 8; ++k) { sA = fma(ea64[k], ra[k], sA); sB = fma(eb64[k], rb[k], sB); }
            if (sA > bva) { bva = sA; ba = e; }                  // strict >: keeps smallest e per lane
            if (sB > bvb) { bvb = sB; bb = e; }
        }
#pragma unroll
        for (int off = 32; off > 0; off >>= 1) {
            double ov = __shfl_xor(bva, off); int oi = __shfl_xor(ba, off);
            if (ov > bva || (ov == bva && oi < ba)) { bva = ov; ba = oi; }
            ov = __shfl_xor(bvb, off); oi = __shfl_xor(bb, off);
            if (ov > bvb || (ov == bvb && oi < bb)) { bvb = ov; bb = oi; }
        }
        if (lane == 0) idxAB[fr] = (ba << 12) | bb;
    }
}

// ================= E: idx output + deterministic loss partials; 128 blocks x 256 =================
__global__ void __launch_bounds__(256, 4)
vq_emit(const int* __restrict__ idxAB, const double* __restrict__ za64,
        const float* __restrict__ cb_a, const float* __restrict__ cb_b,
        float* __restrict__ out, double* __restrict__ part) {
    const int tid = threadIdx.x;
    const int f   = blockIdx.x * 256 + tid;

    const int code = idxAB[f];
    const int iA = code >> 12, iB = code & 4095;
    out[IDX_OFF + (size_t)f] = (float)code;                      // < 2^24: exact in f32

    const float4 qa0 = *(const float4*)(cb_a + (size_t)iA * CDIM);
    const float4 qa1 = *(const float4*)(cb_a + (size_t)iA * CDIM + 4);
    const float4 qb0 = *(const float4*)(cb_b + (size_t)iB * CDIM);
    const float4 qb1 = *(const float4*)(cb_b + (size_t)iB * CDIM + 4);
    const float zaq[8] = {qa0.x, qa0.y, qa0.z, qa0.w, qa1.x, qa1.y, qa1.z, qa1.w};
    const float zbq[8] = {qb0.x, qb0.y, qb0.z, qb0.w, qb1.x, qb1.y, qb1.z, qb1.w};

    const double* zp = za64 + (size_t)f * 16;
    double s = 0.0;
#pragma unroll
    for (int k = 0; k < 8; ++k) {
        const double d0 = zp[k]     - (double)zaq[k]; s = fma(d0, d0, s);
        const double d1 = zp[8 + k] - (double)zbq[k]; s = fma(d1, d1, s);
    }

    __shared__ double sred[256];
    sred[tid] = s;
    __syncthreads();
#pragma unroll
    for (int off = 128; off > 0; off >>= 1) {                    // fixed tree: deterministic
        if (tid < off) sred[tid] += sred[tid + off];
        __syncthreads();
    }
    if (tid == 0) part[blockIdx.x] = sred[0];
}

// ================= F: streaming out-projection with direct gather; 2048 blocks x 256 =================
__global__ void __launch_bounds__(256, 4)
vq_store(const int* __restrict__ idxAB,
         const float* __restrict__ cb_a, const float* __restrict__ cb_b,
         const float* __restrict__ w_out_a, const float* __restrict__ b_out_a,
         const float* __restrict__ w_out_b, const float* __restrict__ b_out_b,
         float* __restrict__ out) {
    const int tid  = threadIdx.x;
    const int lane = tid & 63;
    const int wave = __builtin_amdgcn_readfirstlane(tid >> 6);   // 0..3
    const int blk  = blockIdx.x;
    const int b    = blk >> 8;
    const int rem  = blk & 255;
    const int tt   = rem >> 4;                                   // 16 t-tiles of 256
    const int ct   = rem & 15;                                   // 16 c-tiles of 64
    const int t0   = (tt << 8) + (lane << 2);
    const int f0   = (b << 12) + t0;

    const bool bookb = (ct >= 8);
    const float* wO = bookb ? w_out_b : w_out_a;
    const float* bO = bookb ? b_out_b : b_out_a;
    const float* cbp = bookb ? cb_b : cb_a;

    const int4 codes = *(const int4*)(idxAB + f0);
    float qv[4][8];
    {
        const int cd[4] = {codes.x, codes.y, codes.z, codes.w};
#pragma unroll
        for (int j = 0; j < 4; ++j) {
            const int idx = bookb ? (cd[j] & 4095) : (cd[j] >> 12);
            const float4 q0 = *(const float4*)(cbp + (size_t)idx * CDIM);
            const float4 q1 = *(const float4*)(cbp + (size_t)idx * CDIM + 4);
            qv[j][0]=q0.x; qv[j][1]=q0.y; qv[j][2]=q0.z; qv[j][3]=q0.w;
            qv[j][4]=q1.x; qv[j][5]=q1.y; qv[j][6]=q1.z; qv[j][7]=q1.w;
        }
    }

    const int cl0 = ((ct & 7) << 6) + (wave << 4);               // local channel in half
#pragma unroll 4
    for (int cc = 0; cc < 16; ++cc) {
        const int cl = cl0 + cc;
        const float* wr = wO + (size_t)cl * 8;                   // uniform -> s_load
        const float bias = bO[cl];
        float4 o = make_float4(bias, bias, bias, bias);
#pragma unroll
        for (int k = 0; k < 8; ++k) {
            o.x = fmaf(wr[k], qv[0][k], o.x);
            o.y = fmaf(wr[k], qv[1][k], o.y);
            o.z = fmaf(wr[k], qv[2][k], o.z);
            o.w = fmaf(wr[k], qv[3][k], o.w);
        }
        const int c = (bookb ? 512 : 0) + cl;
        *(float4*)(out + ((size_t)b * ND + c) * NT + t0) = o;
    }
}

__global__ void vq_finalize(const double* __restrict__ part, float* __restrict__ out) {
    const int b = threadIdx.x;
    if (b < NB) {
        double s = 0.0;
        for (int j = 0; j < 16; ++j) s += part[b * 16 + j];      // fixed order: deterministic
        const float v = (float)(s * (1.0 / 32768.0));
        out[CL_OFF + b]  = v;
        out[CBL_OFF + b] = v;
    }
}

// ================= fallback monolith (round-1 proven, if ws too small) =================
__global__ void __launch_bounds__(256, 2)
vq_mono(const float* __restrict__ z,
        const float* __restrict__ w_in_a, const float* __restrict__ b_in_a,
        const float* __restrict__ w_in_b, const float* __restrict__ b_in_b,
        const float* __restrict__ w_out_a, const float* __restrict__ b_out_a,
        const float* __restrict__ w_out_b, const float* __restrict__ b_out_b,
        const float* __restrict__ cb_a, const float* __restrict__ cb_b,
        float* __restrict__ out, double* __restrict__ part) {
    const int tid  = threadIdx.x;
    const int lane = tid & 63;
    const int wave = __builtin_amdgcn_readfirstlane(tid >> 6);
    const int blk  = blockIdx.x;
    const int b    = blk >> 6;
    const int t    = ((blk & 63) << 6) + lane;

    __shared__ double red[4][64][9];
    __shared__ double sBest[2][4][64];
    __shared__ int    sIdx[2][4][64];

    double acc[16];
#pragma unroll
    for (int k = 0; k < 16; ++k) acc[k] = 0.0;
    const float* zp = z + ((size_t)b * ND) * NT + t;
    const int i0 = wave * 256;
#pragma unroll 2
    for (int ii = 0; ii < 256; ++ii) {
        const int i = i0 + ii;
        const double zd = (double)zp[(size_t)i * NT];
#pragma unroll
        for (int o = 0; o < 8; ++o) {
            acc[o]     = fma((double)w_in_a[o * ND + i], zd, acc[o]);
            acc[8 + o] = fma((double)w_in_b[o * ND + i], zd, acc[8 + o]);
        }
    }
    double za[16];
#pragma unroll
    for (int r = 0; r < 2; ++r) {
#pragma unroll
        for (int k = 0; k < 8; ++k) red[wave][lane][k] = acc[8 * r + k];
        __syncthreads();
#pragma unroll
        for (int k = 0; k < 8; ++k)
            za[8*r+k] = ((red[0][lane][k] + red[1][lane][k]) + red[2][lane][k]) + red[3][lane][k];
        __syncthreads();
    }
#pragma unroll
    for (int k = 0; k < 8; ++k) { za[k] += (double)b_in_a[k]; za[8 + k] += (double)b_in_b[k]; }

    if (wave == 0) {
#pragma unroll
        for (int k = 0; k < 16; ++k)
            out[LAT_OFF + ((size_t)b * 16 + k) * NT + t] = (float)za[k];
    }

    double ea[8], eb[8];
    {
        double n2 = 0.0;
#pragma unroll
        for (int k = 0; k < 8; ++k) n2 = fma(za[k], za[k], n2);
        double inv = 1.0 / fmax(sqrt(n2), 1e-12);
#pragma unroll
        for (int k = 0; k < 8; ++k) ea[k] = za[k] * inv;
    }
    {
        double n2 = 0.0;
#pragma unroll
        for (int k = 0; k < 8; ++k) n2 = fma(za[8 + k], za[8 + k], n2);
        double inv = 1.0 / fmax(sqrt(n2), 1e-12);
#pragma unroll
        for (int k = 0; k < 8; ++k) eb[k] = za[8 + k] * inv;
    }

    double bestA = -1e300, bestB = -1e300;
    int ibA = 0, ibB = 0;
    const int j0 = wave << 10;
    for (int jj = 0; jj < 1024; ++jj) {
        const int j = j0 + jj;
        const float* ra = cb_a + (size_t)j * CDIM;
        const float* rb = cb_b + (size_t)j * CDIM;
        double na = 0.0, nb = 0.0, sA = 0.0, sB = 0.0;
#pragma unroll
        for (int k = 0; k < 8; ++k) {
            double av = (double)ra[k], bv2 = (double)rb[k];
            na = fma(av, av, na); nb = fma(bv2, bv2, nb);
            sA = fma(ea[k], av, sA); sB = fma(eb[k], bv2, sB);
        }
        sA /= fmax(sqrt(na), 1e-12);
        sB /= fmax(sqrt(nb), 1e-12);
        if (sA > bestA) { bestA = sA; ibA = j; }
        if (sB > bestB) { bestB = sB; ibB = j; }
    }
    sBest[0][wave][lane] = bestA; sIdx[0][wave][lane] = ibA;
    sBest[1][wave][lane] = bestB; sIdx[1][wave][lane] = ibB;
    __syncthreads();

    double bA = sBest[0][0][lane]; int iA = sIdx[0][0][lane];
    double bB = sBest[1][0][lane]; int iB = sIdx[1][0][lane];
#pragma unroll
    for (int w2 = 1; w2 < 4; ++w2) {
        double d = sBest[0][w2][lane]; int j2 = sIdx[0][w2][lane];
        if (d > bA) { bA = d; iA = j2; }
        d = sBest[1][w2][lane]; j2 = sIdx[1][w2][lane];
        if (d > bB) { bB = d; iB = j2; }
    }

    float4 qa0 = *(const float4*)(cb_a + (size_t)iA * CDIM);
    float4 qa1 = *(const float4*)(cb_a + (size_t)iA * CDIM + 4);
    float4 qb0 = *(const float4*)(cb_b + (size_t)iB * CDIM);
    float4 qb1 = *(const float4*)(cb_b + (size_t)iB * CDIM + 4);
    float zaq[8] = {qa0.x, qa0.y, qa0.z, qa0.w, qa1.x, qa1.y, qa1.z, qa1.w};
    float zbq[8] = {qb0.x, qb0.y, qb0.z, qb0.w, qb1.x, qb1.y, qb1.z, qb1.w};

    if (wave == 0) {
        out[IDX_OFF + (size_t)b * NT + t] = (float)(iA * CSZ + iB);
        double s = 0.0;
#pragma unroll
        for (int k = 0; k < 8; ++k) {
            double d0 = za[k]     - (double)zaq[k]; s = fma(d0, d0, s);
            double d1 = za[8 + k] - (double)zbq[k]; s = fma(d1, d1, s);
        }
#pragma unroll
        for (int off = 32; off > 0; off >>= 1) s += __shfl_down(s, off);
        if (lane == 0) part[blk] = s;
    }

    const int c0 = wave << 7;
    const size_t obase = ((size_t)b * ND) * NT + t;
    for (int cc = 0; cc < 128; ++cc) {
        const int c = c0 + cc;
        const float* wa = w_out_a + (size_t)c * CDIM;
        const float* wb = w_out_b + (size_t)c * CDIM;
        float sa = b_out_a[c], sb = b_out_b[c];
#pragma unroll
        for (int k = 0; k < 8; ++k) { sa = fmaf(wa[k], zaq[k], sa); sb = fmaf(wb[k], zbq[k], sb); }
        out[obase + (size_t)c * NT]         = sa;
        out[obase + (size_t)(512 + c) * NT] = sb;
    }
}

__global__ void vq_finalize64(const double* __restrict__ part, float* __restrict__ out) {
    const int b = threadIdx.x;
    if (b < NB) {
        double s = 0.0;
        for (int j = 0; j < 64; ++j) s += part[(size_t)b * 64 + j];
        const float v = (float)(s * (1.0 / 32768.0));
        out[CL_OFF + b]  = v;
        out[CBL_OFF + b] = v;
    }
}

extern "C" void kernel_launch(void* const* d_in, const int* in_sizes, int n_in,
                              void* d_out, int out_size, void* d_ws, size_t ws_size,
                              hipStream_t stream) {
    const float* z       = (const float*)d_in[0];
    const float* w_in_a  = (const float*)d_in[1];
    const float* b_in_a  = (const float*)d_in[2];
    const float* w_in_b  = (const float*)d_in[3];
    const float* b_in_b  = (const float*)d_in[4];
    const float* w_out_a = (const float*)d_in[5];
    const float* b_out_a = (const float*)d_in[6];
    const float* w_out_b = (const float*)d_in[7];
    const float* b_out_b = (const float*)d_in[8];
    const float* cb_a    = (const float*)d_in[9];
    const float* cb_b    = (const float*)d_in[10];
    float* out = (float*)d_out;
    char* ws = (char*)d_ws;

    if (ws_size >= WS_NEED) {
        double* wT64   = (double*)(ws + WT64_B);
        double* cbn64A = (double*)(ws + CBN64A_B);
        double* cbn64B = (double*)(ws + CBN64B_B);
        float*  cbn32A = (float*) (ws + CBN32A_B);
        float*  cbn32B = (float*) (ws + CBN32B_B);
        double* za64   = (double*)(ws + ZA64_B);
        float*  e32    = (float*) (ws + E32_B);
        double* bv     = (double*)(ws + BV_B);
        int*    idxAB  = (int*)   (ws + IDXW_B);
        int*    list   = (int*)   (ws + LIST_B);
        int*    cnt    = (int*)   (ws + CNT_B);
        double* part   = (double*)(ws + PART_B);

        vq_prep<<<96, 256, 0, stream>>>(w_in_a, w_in_b, cb_a, cb_b,
                                        wT64, cbn64A, cbn64B, cbn32A, cbn32B, cnt);
        vq_proj<<<512, 512, 0, stream>>>(z, b_in_a, b_in_b, wT64, za64, e32, out);
        vq_scan<<<2048, 256, 0, stream>>>(e32, cbn32A, cbn32B, bv);
        vq_sel<<<128, 256, 0, stream>>>(bv, idxAB, list, cnt);
        vq_rescue<<<1024, 64, 0, stream>>>(list, cnt, za64, cbn64A, cbn64B, idxAB);
        vq_emit<<<128, 256, 0, stream>>>(idxAB, za64, cb_a, cb_b, out, part);
        vq_store<<<2048, 256, 0, stream>>>(idxAB, cb_a, cb_b,
                                           w_out_a, b_out_a, w_out_b, b_out_b, out);
        vq_finalize<<<1, 64, 0, stream>>>(part, out);
    } else {
        double* part = (double*)ws;
        vq_mono<<<512, 256, 0, stream>>>(z, w_in_a, b_in_a, w_in_b, b_in_b,
                                         w_out_a, b_out_a, w_out_b, b_out_b,
                                         cb_a, cb_b, out, part);
        vq_finalize64<<<1, 64, 0, stream>>>(part, out);
    }
}

// Round 5
// 183.522 us; speedup vs baseline: 1.8743x; 1.2776x over previous
//
#include <hip/hip_runtime.h>
#include <math.h>

#define CDIM 8
#define CSZ  4096
#define NB   8
#define ND   1024
#define NT   4096
#define NFR  (NB * NT)               // 32768 frames
#define TAU  1.2e-4f                 // f16-split-MFMA vs f64 sim safety gap (delta <= ~1e-5)

typedef float  f32x4 __attribute__((ext_vector_type(4)));
typedef _Float16 f16x8 __attribute__((ext_vector_type(8)));

// ---- d_out layout (flat f32, return order) ----
static constexpr size_t CL_OFF  = (size_t)NB * ND * NT;
static constexpr size_t CBL_OFF = CL_OFF + NB;
static constexpr size_t IDX_OFF = CBL_OFF + NB;
static constexpr size_t LAT_OFF = IDX_OFF + (size_t)NB * NT;

// ---- d_ws layout (byte offsets, all 16B aligned) ----
static constexpr size_t WT64_B   = 0;                         // f64[16384] w_in transposed [i][16]
static constexpr size_t CBN64A_B = 131072;                    // f64[4096*8]
static constexpr size_t CBN64B_B = 393216;                    // f64[4096*8]
static constexpr size_t CARR_B   = 655360;                    // f16 [book][g][4096][8] = 512 KB
static constexpr size_t ZA64_B   = 1179648;                   // f64[NFR*16]
static constexpr size_t EARR_B   = 5373952;                   // f16 [frame][book][g][8] = 4 MB
static constexpr size_t IDXW_B   = 9568256;                   // i32[NFR] packed (iA<<12)|iB
static constexpr size_t LIST_B   = 9699328;                   // i32[NFR] needy list
static constexpr size_t CNT_B    = 9830400;                   // i32 counter (+pad)
static constexpr size_t PART_B   = 9830464;                   // f64[128] loss partials
static constexpr size_t WS_NEED  = PART_B + 128 * 8;          // ~9.4 MB

// split x into f16 hi + lo with 2^6 scaling so no slot risks denorm-flush loss:
// sim term pairing: g0: chi*ehi, g1: (chi/64)*(elo*64), g2: (clo*64)*(ehi/64), g3: 0
__device__ __forceinline__ void split16(float x, _Float16& hi, _Float16& lo64, _Float16& hi64) {
    const _Float16 h = (fabsf(x) < 0.0009765625f) ? (_Float16)0.f : (_Float16)x;  // |x|<2^-10 -> all-lo
    const float hf = (float)h;
    hi   = h;
    lo64 = (_Float16)((x - hf) * 64.f);
    hi64 = (_Float16)(hf * 0.015625f);
}

// ================= prep: wT64 + f64-normalized codebooks + f16-split carray =================
__global__ void vq_prep(const float* __restrict__ w_in_a, const float* __restrict__ w_in_b,
                        const float* __restrict__ cb_a,  const float* __restrict__ cb_b,
                        double* __restrict__ wT64,
                        double* __restrict__ cbn64A, double* __restrict__ cbn64B,
                        float4* __restrict__ carr, int* __restrict__ cnt) {
    int id = blockIdx.x * 256 + threadIdx.x;
    if (id == 0) *cnt = 0;
    if (id < 16384) {
        int i = id >> 4, o = id & 15;
        float w = (o < 8) ? w_in_a[o * ND + i] : w_in_b[(o - 8) * ND + i];
        wT64[id] = (double)w;
    } else if (id < 16384 + 2 * CSZ) {
        int e = id - 16384;
        int book = e >> 12, j = e & (CSZ - 1);
        const float* src = (book ? cb_b : cb_a) + (size_t)j * CDIM;
        double* d64 = (book ? cbn64B : cbn64A) + (size_t)j * CDIM;
        double c[CDIM]; double n2 = 0.0;
#pragma unroll
        for (int k = 0; k < CDIM; ++k) { c[k] = (double)src[k]; n2 = fma(c[k], c[k], n2); }
        double den = fmax(sqrt(n2), 1e-12);
        f16x8 g0, g1, g2, g3;
#pragma unroll
        for (int k = 0; k < CDIM; ++k) {
            double v = c[k] / den;
            d64[k] = v;
            _Float16 hi, lo64, hi64;
            split16((float)v, hi, lo64, hi64);
            g0[k] = hi; g1[k] = hi64; g2[k] = lo64; g3[k] = (_Float16)0.f;
        }
        const size_t base = (size_t)(book << 2) * CSZ + j;
        carr[base]           = *(float4*)&g0;
        carr[base + CSZ]     = *(float4*)&g1;
        carr[base + 2 * CSZ] = *(float4*)&g2;
        carr[base + 3 * CSZ] = *(float4*)&g3;
    }
}

// ================= A: f64 projection + normalize + f16-split enc; 512 blocks x 512 =================
__global__ void __launch_bounds__(512, 4)
vq_proj(const float* __restrict__ z,
        const float* __restrict__ b_in_a, const float* __restrict__ b_in_b,
        const double* __restrict__ wT64,
        double* __restrict__ za64, float4* __restrict__ earr,
        float* __restrict__ out) {
    const int tid  = threadIdx.x;
    const int lane = tid & 63;
    const int wave = __builtin_amdgcn_readfirstlane(tid >> 6);  // 0..7
    const int blk  = blockIdx.x;
    const int b    = blk >> 6;
    const int t    = ((blk & 63) << 6) + lane;
    const int f    = (blk << 6) + lane;

    __shared__ double red[8][64][9];                            // 36.9 KB

    double acc[16];
#pragma unroll
    for (int k = 0; k < 16; ++k) acc[k] = 0.0;

    const float* zp = z + ((size_t)b * ND) * NT + t;
    const int i0 = wave * 128;
#pragma unroll 4
    for (int ii = 0; ii < 128; ++ii) {
        const int i = i0 + ii;
        const double zd = (double)zp[(size_t)i * NT];
        const double* wr = wT64 + (size_t)i * 16;               // uniform -> s_load
#pragma unroll
        for (int k = 0; k < 16; ++k) acc[k] = fma(wr[k], zd, acc[k]);
    }

    double za16[16];
#pragma unroll
    for (int r = 0; r < 2; ++r) {
#pragma unroll
        for (int k = 0; k < 8; ++k) red[wave][lane][k] = acc[8 * r + k];
        __syncthreads();
        if (wave == 0) {
#pragma unroll
            for (int k = 0; k < 8; ++k) {
                double s = red[0][lane][k];
#pragma unroll
                for (int w = 1; w < 8; ++w) s += red[w][lane][k];
                za16[8 * r + k] = s;
            }
        }
        __syncthreads();
    }
    if (wave != 0) return;

#pragma unroll
    for (int k = 0; k < 8; ++k) { za16[k] += (double)b_in_a[k]; za16[8 + k] += (double)b_in_b[k]; }

    // latent output (f32)
#pragma unroll
    for (int k = 0; k < 16; ++k)
        out[LAT_OFF + ((size_t)b * 16 + k) * NT + t] = (float)za16[k];

    // store za64 (for rescue + losses)
    double* zf = za64 + (size_t)f * 16;
#pragma unroll
    for (int k = 0; k < 16; ++k) zf[k] = za16[k];

    // normalize in f64, f16-split, write earray slots [frame][book][g]
    double n2a = 0.0, n2b = 0.0;
#pragma unroll
    for (int k = 0; k < 8; ++k) { n2a = fma(za16[k], za16[k], n2a); n2b = fma(za16[8+k], za16[8+k], n2b); }
    const double ia_ = 1.0 / fmax(sqrt(n2a), 1e-12);
    const double ib_ = 1.0 / fmax(sqrt(n2b), 1e-12);
#pragma unroll
    for (int book = 0; book < 2; ++book) {
        const double inv = book ? ib_ : ia_;
        f16x8 g0, g1, g2, g3;
#pragma unroll
        for (int k = 0; k < 8; ++k) {
            const float e32 = (float)(za16[book * 8 + k] * inv);
            _Float16 hi, lo64, hi64;
            split16(e32, hi, lo64, hi64);
            g0[k] = hi; g1[k] = lo64; g2[k] = hi64; g3[k] = (_Float16)0.f;
        }
        const size_t base = (size_t)f * 8 + book * 4;
        earr[base]     = *(float4*)&g0;
        earr[base + 1] = *(float4*)&g1;
        earr[base + 2] = *(float4*)&g2;
        earr[base + 3] = *(float4*)&g3;
    }
}

// ================= B: MFMA prescan; 512 blocks x 256 thr, wave = 16 frames =================
#define TRACK(BOOK) \
    _Pragma("unroll 4") \
    for (int t = 0; t < 64; ++t) { \
        float4 araw = lc[t * 16 + col]; \
        f16x8 af = *(f16x8*)&araw; \
        f32x4 acc = __builtin_amdgcn_mfma_f32_16x16x32_f16(af, bf##BOOK, zc, 0, 0, 0); \
        const int tg = cb16 + t; \
        _Pragma("unroll") \
        for (int r = 0; r < 4; ++r) { \
            const float s = acc[r]; \
            const bool gt = s > b1##BOOK[r]; \
            b2##BOOK[r] = fmaxf(b2##BOOK[r], gt ? b1##BOOK[r] : s); \
            b1##BOOK[r] = gt ? s : b1##BOOK[r]; \
            bt##BOOK[r] = gt ? tg : bt##BOOK[r]; \
        } \
    }

__global__ void __launch_bounds__(256, 2)
vq_scan_mfma(const float4* __restrict__ carr, const float4* __restrict__ earr,
             int* __restrict__ idxAB, int* __restrict__ list, int* __restrict__ cnt) {
    __shared__ float4 ldsc[4096];                               // 64 KB: [g][1024 entries]
    const int tid  = threadIdx.x;
    const int lane = tid & 63;
    const int wave = __builtin_amdgcn_readfirstlane(tid >> 6);  // 0..3
    const int col  = lane & 15;                                 // frame-local
    const int g    = lane >> 4;                                 // k-group / C-row-group
    const int f    = blockIdx.x * 64 + wave * 16 + col;

    const f16x8* ep = (const f16x8*)earr;
    const f16x8 bfA = ep[(size_t)f * 8 + g];                    // book 0, slot g
    const f16x8 bfB = ep[(size_t)f * 8 + 4 + g];                // book 1, slot g
    const f32x4 zc = {0.f, 0.f, 0.f, 0.f};

    float b1A[4], b2A[4], b1B[4], b2B[4];
    int   btA[4], btB[4];
#pragma unroll
    for (int r = 0; r < 4; ++r) {
        b1A[r] = b2A[r] = b1B[r] = b2B[r] = -1e30f;
        btA[r] = btB[r] = 0;
    }

    for (int ch = 0; ch < 8; ++ch) {
        const int book = ch >> 2;
        const int cb16 = (ch & 3) << 6;                          // tile base within book
        __syncthreads();
#pragma unroll
        for (int it = 0; it < 16; ++it) {
            const int idx = it * 256 + tid;                      // chunk slot: g'=idx>>10, e=idx&1023
            ldsc[idx] = carr[(size_t)((book << 2) + (idx >> 10)) * CSZ
                             + ((ch & 3) << 10) + (idx & 1023)];
        }
        __syncthreads();
        const float4* lc = ldsc + g * 1024;                      // this lane's g-plane (reads linear)
        if (book == 0) { TRACK(A) } else { TRACK(B) }
    }

    // per-lane top across regs -> (v1, e1, v2) per book; entry = tile*16 + g*4 + r
    float v1A = b1A[0], v2A = b2A[0]; int e1A = btA[0] * 16 + g * 4;
    float v1B = b1B[0], v2B = b2B[0]; int e1B = btB[0] * 16 + g * 4;
#pragma unroll
    for (int r = 1; r < 4; ++r) {
        {
            const float c1 = b1A[r]; const int ce = btA[r] * 16 + g * 4 + r; const float c2 = b2A[r];
            const float n2 = fmaxf(fminf(v1A, c1), fmaxf(v2A, c2));
            const bool tk = (c1 > v1A) || (c1 == v1A && ce < e1A);
            v1A = tk ? c1 : v1A; e1A = tk ? ce : e1A; v2A = n2;
        }
        {
            const float c1 = b1B[r]; const int ce = btB[r] * 16 + g * 4 + r; const float c2 = b2B[r];
            const float n2 = fmaxf(fminf(v1B, c1), fmaxf(v2B, c2));
            const bool tk = (c1 > v1B) || (c1 == v1B && ce < e1B);
            v1B = tk ? c1 : v1B; e1B = tk ? ce : e1B; v2B = n2;
        }
    }
    // cross-group reduce: lanes l, l^16, l^32, l^48 share the same frame (col)
#pragma unroll
    for (int off = 16; off <= 32; off <<= 1) {
        {
            const float o1 = __shfl_xor(v1A, off); const int oe = __shfl_xor(e1A, off);
            const float o2 = __shfl_xor(v2A, off);
            const float n2 = fmaxf(fminf(v1A, o1), fmaxf(v2A, o2));
            const bool tk = (o1 > v1A) || (o1 == v1A && oe < e1A);
            v1A = tk ? o1 : v1A; e1A = tk ? oe : e1A; v2A = n2;
        }
        {
            const float o1 = __shfl_xor(v1B, off); const int oe = __shfl_xor(e1B, off);
            const float o2 = __shfl_xor(v2B, off);
            const float n2 = fmaxf(fminf(v1B, o1), fmaxf(v2B, o2));
            const bool tk = (o1 > v1B) || (o1 == v1B && oe < e1B);
            v1B = tk ? o1 : v1B; e1B = tk ? oe : e1B; v2B = n2;
        }
    }

    if (lane < 16) {
        idxAB[f] = (e1A << 12) | e1B;
        const bool needy = ((v1A - v2A) < TAU) || ((v1B - v2B) < TAU);
        if (needy) { const int p = atomicAdd(cnt, 1); list[p] = f; }
    }
}

// ================= D: exact f64 rescue, one wave per needy frame; 256 blocks x 256 =================
__global__ void __launch_bounds__(256, 4)
vq_rescue(const int* __restrict__ list, const int* __restrict__ cnt,
          const double* __restrict__ za64,
          const double* __restrict__ cbn64A, const double* __restrict__ cbn64B,
          int* __restrict__ idxAB) {
    const int lane = threadIdx.x & 63;
    const int wv   = (blockIdx.x << 2) + (threadIdx.x >> 6);
    const int n = *cnt;
    for (int it = wv; it < n; it += 1024) {
        const int fr = list[it];
        const double* zr = za64 + (size_t)fr * 16;               // uniform -> s_load
        double zra[16];
#pragma unroll
        for (int k = 0; k < 16; ++k) zra[k] = zr[k];
        double n2a = 0.0, n2b = 0.0;
#pragma unroll
        for (int k = 0; k < 8; ++k) { n2a = fma(zra[k], zra[k], n2a); n2b = fma(zra[8+k], zra[8+k], n2b); }
        const double ja_ = 1.0 / fmax(sqrt(n2a), 1e-12);
        const double jb_ = 1.0 / fmax(sqrt(n2b), 1e-12);
        double ea64[8], eb64[8];
#pragma unroll
        for (int k = 0; k < 8; ++k) { ea64[k] = zra[k] * ja_; eb64[k] = zra[8 + k] * jb_; }

        double bva = -1e300, bvb = -1e300; int ba = 0, bb = 0;
        for (int e = lane; e < CSZ; e += 64) {                   // lane-strided: coalesced
            const double* ra = cbn64A + (size_t)e * 8;
            const double* rb = cbn64B + (size_t)e * 8;
            double sA = 0.0, sB = 0.0;
#pragma unroll
            for (int k = 0; k < 8; ++k) { sA = fma(ea64[k], ra[k], sA); sB = fma(eb64[k], rb[k], sB); }
            if (sA > bva) { bva = sA; ba = e; }
            if (sB > bvb) { bvb = sB; bb = e; }
        }
#pragma unroll
        for (int off = 32; off > 0; off >>= 1) {
            double ov = __shfl_xor(bva, off); int oi = __shfl_xor(ba, off);
            if (ov > bva || (ov == bva && oi < ba)) { bva = ov; ba = oi; }
            ov = __shfl_xor(bvb, off); oi = __shfl_xor(bb, off);
            if (ov > bvb || (ov == bvb && oi < bb)) { bvb = ov; bb = oi; }
        }
        if (lane == 0) idxAB[fr] = (ba << 12) | bb;
    }
}

// ================= E: idx output + deterministic loss partials; 128 blocks x 256 =================
__global__ void __launch_bounds__(256, 4)
vq_emit(const int* __restrict__ idxAB, const double* __restrict__ za64,
        const float* __restrict__ cb_a, const float* __restrict__ cb_b,
        float* __restrict__ out, double* __restrict__ part) {
    const int tid = threadIdx.x;
    const int f   = blockIdx.x * 256 + tid;

    const int code = idxAB[f];
    const int iA = code >> 12, iB = code & 4095;
    out[IDX_OFF + (size_t)f] = (float)code;                      // < 2^24: exact in f32

    const float4 qa0 = *(const float4*)(cb_a + (size_t)iA * CDIM);
    const float4 qa1 = *(const float4*)(cb_a + (size_t)iA * CDIM + 4);
    const float4 qb0 = *(const float4*)(cb_b + (size_t)iB * CDIM);
    const float4 qb1 = *(const float4*)(cb_b + (size_t)iB * CDIM + 4);
    const float zaq[8] = {qa0.x, qa0.y, qa0.z, qa0.w, qa1.x, qa1.y, qa1.z, qa1.w};
    const float zbq[8] = {qb0.x, qb0.y, qb0.z, qb0.w, qb1.x, qb1.y, qb1.z, qb1.w};

    const double* zp = za64 + (size_t)f * 16;
    double s = 0.0;
#pragma unroll
    for (int k = 0; k < 8; ++k) {
        const double d0 = zp[k]     - (double)zaq[k]; s = fma(d0, d0, s);
        const double d1 = zp[8 + k] - (double)zbq[k]; s = fma(d1, d1, s);
    }

    __shared__ double sred[256];
    sred[tid] = s;
    __syncthreads();
#pragma unroll
    for (int off = 128; off > 0; off >>= 1) {                    // fixed tree: deterministic
        if (tid < off) sred[tid] += sred[tid + off];
        __syncthreads();
    }
    if (tid == 0) part[blockIdx.x] = sred[0];
}

// ================= F: streaming out-projection with direct gather; 2048 blocks x 256 =================
__global__ void __launch_bounds__(256, 4)
vq_store(const int* __restrict__ idxAB,
         const float* __restrict__ cb_a, const float* __restrict__ cb_b,
         const float* __restrict__ w_out_a, const float* __restrict__ b_out_a,
         const float* __restrict__ w_out_b, const float* __restrict__ b_out_b,
         float* __restrict__ out) {
    const int tid  = threadIdx.x;
    const int lane = tid & 63;
    const int wave = __builtin_amdgcn_readfirstlane(tid >> 6);   // 0..3
    const int blk  = blockIdx.x;
    const int b    = blk >> 8;
    const int rem  = blk & 255;
    const int tt   = rem >> 4;                                   // 16 t-tiles of 256
    const int ct   = rem & 15;                                   // 16 c-tiles of 64
    const int t0   = (tt << 8) + (lane << 2);
    const int f0   = (b << 12) + t0;

    const bool bookb = (ct >= 8);
    const float* wO = bookb ? w_out_b : w_out_a;
    const float* bO = bookb ? b_out_b : b_out_a;
    const float* cbp = bookb ? cb_b : cb_a;

    const int4 codes = *(const int4*)(idxAB + f0);
    float qv[4][8];
    {
        const int cd[4] = {codes.x, codes.y, codes.z, codes.w};
#pragma unroll
        for (int j = 0; j < 4; ++j) {
            const int idx = bookb ? (cd[j] & 4095) : (cd[j] >> 12);
            const float4 q0 = *(const float4*)(cbp + (size_t)idx * CDIM);
            const float4 q1 = *(const float4*)(cbp + (size_t)idx * CDIM + 4);
            qv[j][0]=q0.x; qv[j][1]=q0.y; qv[j][2]=q0.z; qv[j][3]=q0.w;
            qv[j][4]=q1.x; qv[j][5]=q1.y; qv[j][6]=q1.z; qv[j][7]=q1.w;
        }
    }

    const int cl0 = ((ct & 7) << 6) + (wave << 4);               // local channel in half
#pragma unroll 4
    for (int cc = 0; cc < 16; ++cc) {
        const int cl = cl0 + cc;
        const float* wr = wO + (size_t)cl * 8;                   // uniform -> s_load
        const float bias = bO[cl];
        float4 o = make_float4(bias, bias, bias, bias);
#pragma unroll
        for (int k = 0; k < 8; ++k) {
            o.x = fmaf(wr[k], qv[0][k], o.x);
            o.y = fmaf(wr[k], qv[1][k], o.y);
            o.z = fmaf(wr[k], qv[2][k], o.z);
            o.w = fmaf(wr[k], qv[3][k], o.w);
        }
        const int c = (bookb ? 512 : 0) + cl;
        *(float4*)(out + ((size_t)b * ND + c) * NT + t0) = o;
    }
}

__global__ void vq_finalize(const double* __restrict__ part, float* __restrict__ out) {
    const int b = threadIdx.x;
    if (b < NB) {
        double s = 0.0;
        for (int j = 0; j < 16; ++j) s += part[b * 16 + j];      // fixed order: deterministic
        const float v = (float)(s * (1.0 / 32768.0));
        out[CL_OFF + b]  = v;
        out[CBL_OFF + b] = v;
    }
}

// ================= fallback monolith (round-1 proven, if ws too small) =================
__global__ void __launch_bounds__(256, 2)
vq_mono(const float* __restrict__ z,
        const float* __restrict__ w_in_a, const float* __restrict__ b_in_a,
        const float* __restrict__ w_in_b, const float* __restrict__ b_in_b,
        const float* __restrict__ w_out_a, const float* __restrict__ b_out_a,
        const float* __restrict__ w_out_b, const float* __restrict__ b_out_b,
        const float* __restrict__ cb_a, const float* __restrict__ cb_b,
        float* __restrict__ out, double* __restrict__ part) {
    const int tid  = threadIdx.x;
    const int lane = tid & 63;
    const int wave = __builtin_amdgcn_readfirstlane(tid >> 6);
    const int blk  = blockIdx.x;
    const int b    = blk >> 6;
    const int t    = ((blk & 63) << 6) + lane;

    __shared__ double red[4][64][9];
    __shared__ double sBest[2][4][64];
    __shared__ int    sIdx[2][4][64];

    double acc[16];
#pragma unroll
    for (int k = 0; k < 16; ++k) acc[k] = 0.0;
    const float* zp = z + ((size_t)b * ND) * NT + t;
    const int i0 = wave * 256;
#pragma unroll 2
    for (int ii = 0; ii < 256; ++ii) {
        const int i = i0 + ii;
        const double zd = (double)zp[(size_t)i * NT];
#pragma unroll
        for (int o = 0; o < 8; ++o) {
            acc[o]     = fma((double)w_in_a[o * ND + i], zd, acc[o]);
            acc[8 + o] = fma((double)w_in_b[o * ND + i], zd, acc[8 + o]);
        }
    }
    double za[16];
#pragma unroll
    for (int r = 0; r < 2; ++r) {
#pragma unroll
        for (int k = 0; k < 8; ++k) red[wave][lane][k] = acc[8 * r + k];
        __syncthreads();
#pragma unroll
        for (int k = 0; k < 8; ++k)
            za[8*r+k] = ((red[0][lane][k] + red[1][lane][k]) + red[2][lane][k]) + red[3][lane][k];
        __syncthreads();
    }
#pragma unroll
    for (int k = 0; k < 8; ++k) { za[k] += (double)b_in_a[k]; za[8 + k] += (double)b_in_b[k]; }

    if (wave == 0) {
#pragma unroll
        for (int k = 0; k < 16; ++k)
            out[LAT_OFF + ((size_t)b * 16 + k) * NT + t] = (float)za[k];
    }

    double ea[8], eb[8];
    {
        double n2 = 0.0;
#pragma unroll
        for (int k = 0; k < 8; ++k) n2 = fma(za[k], za[k], n2);
        double inv = 1.0 / fmax(sqrt(n2), 1e-12);
#pragma unroll
        for (int k = 0; k < 8; ++k) ea[k] = za[k] * inv;
    }
    {
        double n2 = 0.0;
#pragma unroll
        for (int k = 0; k < 8; ++k) n2 = fma(za[8 + k], za[8 + k], n2);
        double inv = 1.0 / fmax(sqrt(n2), 1e-12);
#pragma unroll
        for (int k = 0; k < 8; ++k) eb[k] = za[8 + k] * inv;
    }

    double bestA = -1e300, bestB = -1e300;
    int ibA = 0, ibB = 0;
    const int j0 = wave << 10;
    for (int jj = 0; jj < 1024; ++jj) {
        const int j = j0 + jj;
        const float* ra = cb_a + (size_t)j * CDIM;
        const float* rb = cb_b + (size_t)j * CDIM;
        double na = 0.0, nb = 0.0, sA = 0.0, sB = 0.0;
#pragma unroll
        for (int k = 0; k < 8; ++k) {
            double av = (double)ra[k], bv2 = (double)rb[k];
            na = fma(av, av, na); nb = fma(bv2, bv2, nb);
            sA = fma(ea[k], av, sA); sB = fma(eb[k], bv2, sB);
        }
        sA /= fmax(sqrt(na), 1e-12);
        sB /= fmax(sqrt(nb), 1e-12);
        if (sA > bestA) { bestA = sA; ibA = j; }
        if (sB > bestB) { bestB = sB; ibB = j; }
    }
    sBest[0][wave][lane] = bestA; sIdx[0][wave][lane] = ibA;
    sBest[1][wave][lane] = bestB; sIdx[1][wave][lane] = ibB;
    __syncthreads();

    double bA = sBest[0][0][lane]; int iA = sIdx[0][0][lane];
    double bB = sBest[1][0][lane]; int iB = sIdx[1][0][lane];
#pragma unroll
    for (int w2 = 1; w2 < 4; ++w2) {
        double d = sBest[0][w2][lane]; int j2 = sIdx[0][w2][lane];
        if (d > bA) { bA = d; iA = j2; }
        d = sBest[1][w2][lane]; j2 = sIdx[1][w2][lane];
        if (d > bB) { bB = d; iB = j2; }
    }

    float4 qa0 = *(const float4*)(cb_a + (size_t)iA * CDIM);
    float4 qa1 = *(const float4*)(cb_a + (size_t)iA * CDIM + 4);
    float4 qb0 = *(const float4*)(cb_b + (size_t)iB * CDIM);
    float4 qb1 = *(const float4*)(cb_b + (size_t)iB * CDIM + 4);
    float zaq[8] = {qa0.x, qa0.y, qa0.z, qa0.w, qa1.x, qa1.y, qa1.z, qa1.w};
    float zbq[8] = {qb0.x, qb0.y, qb0.z, qb0.w, qb1.x, qb1.y, qb1.z, qb1.w};

    if (wave == 0) {
        out[IDX_OFF + (size_t)b * NT + t] = (float)(iA * CSZ + iB);
        double s = 0.0;
#pragma unroll
        for (int k = 0; k < 8; ++k) {
            double d0 = za[k]     - (double)zaq[k]; s = fma(d0, d0, s);
            double d1 = za[8 + k] - (double)zbq[k]; s = fma(d1, d1, s);
        }
#pragma unroll
        for (int off = 32; off > 0; off >>= 1) s += __shfl_down(s, off);
        if (lane == 0) part[blk] = s;
    }

    const int c0 = wave << 7;
    const size_t obase = ((size_t)b * ND) * NT + t;
    for (int cc = 0; cc < 128; ++cc) {
        const int c = c0 + cc;
        const float* wa = w_out_a + (size_t)c * CDIM;
        const float* wb = w_out_b + (size_t)c * CDIM;
        float sa = b_out_a[c], sb = b_out_b[c];
#pragma unroll
        for (int k = 0; k < 8; ++k) { sa = fmaf(wa[k], zaq[k], sa); sb = fmaf(wb[k], zbq[k], sb); }
        out[obase + (size_t)c * NT]         = sa;
        out[obase + (size_t)(512 + c) * NT] = sb;
    }
}

__global__ void vq_finalize64(const double* __restrict__ part, float* __restrict__ out) {
    const int b = threadIdx.x;
    if (b < NB) {
        double s = 0.0;
        for (int j = 0; j < 64; ++j) s += part[(size_t)b * 64 + j];
        const float v = (float)(s * (1.0 / 32768.0));
        out[CL_OFF + b]  = v;
        out[CBL_OFF + b] = v;
    }
}

extern "C" void kernel_launch(void* const* d_in, const int* in_sizes, int n_in,
                              void* d_out, int out_size, void* d_ws, size_t ws_size,
                              hipStream_t stream) {
    const float* z       = (const float*)d_in[0];
    const float* w_in_a  = (const float*)d_in[1];
    const float* b_in_a  = (const float*)d_in[2];
    const float* w_in_b  = (const float*)d_in[3];
    const float* b_in_b  = (const float*)d_in[4];
    const float* w_out_a = (const float*)d_in[5];
    const float* b_out_a = (const float*)d_in[6];
    const float* w_out_b = (const float*)d_in[7];
    const float* b_out_b = (const float*)d_in[8];
    const float* cb_a    = (const float*)d_in[9];
    const float* cb_b    = (const float*)d_in[10];
    float* out = (float*)d_out;
    char* ws = (char*)d_ws;

    if (ws_size >= WS_NEED) {
        double* wT64   = (double*)(ws + WT64_B);
        double* cbn64A = (double*)(ws + CBN64A_B);
        double* cbn64B = (double*)(ws + CBN64B_B);
        float4* carr   = (float4*)(ws + CARR_B);
        double* za64   = (double*)(ws + ZA64_B);
        float4* earr   = (float4*)(ws + EARR_B);
        int*    idxAB  = (int*)   (ws + IDXW_B);
        int*    list   = (int*)   (ws + LIST_B);
        int*    cnt    = (int*)   (ws + CNT_B);
        double* part   = (double*)(ws + PART_B);

        vq_prep<<<96, 256, 0, stream>>>(w_in_a, w_in_b, cb_a, cb_b,
                                        wT64, cbn64A, cbn64B, carr, cnt);
        vq_proj<<<512, 512, 0, stream>>>(z, b_in_a, b_in_b, wT64, za64, earr, out);
        vq_scan_mfma<<<512, 256, 0, stream>>>(carr, earr, idxAB, list, cnt);
        vq_rescue<<<256, 256, 0, stream>>>(list, cnt, za64, cbn64A, cbn64B, idxAB);
        vq_emit<<<128, 256, 0, stream>>>(idxAB, za64, cb_a, cb_b, out, part);
        vq_store<<<2048, 256, 0, stream>>>(idxAB, cb_a, cb_b,
                                           w_out_a, b_out_a, w_out_b, b_out_b, out);
        vq_finalize<<<1, 64, 0, stream>>>(part, out);
    } else {
        double* part = (double*)ws;
        vq_mono<<<512, 256, 0, stream>>>(z, w_in_a, b_in_a, w_in_b, b_in_b,
                                         w_out_a, b_out_a, w_out_b, b_out_b,
                                         cb_a, cb_b, out, part);
        vq_finalize64<<<1, 64, 0, stream>>>(part, out);
    }
}

// Round 6
// 164.165 us; speedup vs baseline: 2.0953x; 1.1179x over previous
//
#include <hip/hip_runtime.h>
#include <math.h>

#define CDIM 8
#define CSZ  4096
#define NB   8
#define ND   1024
#define NT   4096
#define NFR  (NB * NT)               // 32768 frames
#define TAU  4e-5f                   // f16-split-MFMA vs f64 sim gap (analytic delta <= ~8e-6)

typedef float    f32x4  __attribute__((ext_vector_type(4)));
typedef float    f32x16 __attribute__((ext_vector_type(16)));
typedef _Float16 f16x8  __attribute__((ext_vector_type(8)));

// ---- d_out layout (flat f32, return order) ----
static constexpr size_t CL_OFF  = (size_t)NB * ND * NT;
static constexpr size_t CBL_OFF = CL_OFF + NB;
static constexpr size_t IDX_OFF = CBL_OFF + NB;
static constexpr size_t LAT_OFF = IDX_OFF + (size_t)NB * NT;

// ---- d_ws layout (byte offsets, 16B aligned) ----
static constexpr size_t WT64_B   = 0;                          // f64[16384] w_in transposed [i][16]
static constexpr size_t CBN64A_B = 131072;                     // f64[4096*8]
static constexpr size_t CBN64B_B = 393216;                     // f64[4096*8]
static constexpr size_t CARR_B   = 655360;                     // f16x8 [book][plane3][4096] = 384 KB
static constexpr size_t EARR_B   = 1048576;                    // f16x8 [frame][book][slot3] = 3 MB
static constexpr size_t ZA64_B   = 4194304;                    // f64[NFR*16] = 4 MB
static constexpr size_t IDXW_B   = 8388608;                    // i32[NFR] packed (iA<<12)|iB
static constexpr size_t LIST_B   = 8519680;                    // i32[NFR] needy list (f | flags<<16)
static constexpr size_t CNT_B    = 8650752;                    // i32 counter (+pad)
static constexpr size_t PART_B   = 8650816;                    // f64[128] loss partials
static constexpr size_t WS_NEED  = PART_B + 128 * 8;           // ~8.65 MB

// split x: hi (f16) + lo*64 (f16) + hi/64 (f16); |x|<2^-10 routed all-lo (no denorm loss).
// sim = chi*ehi + (chi/64)*(elo*64) + (clo*64)*(ehi/64)
__device__ __forceinline__ void split16(float x, _Float16& hi, _Float16& lo64, _Float16& hi64) {
    const _Float16 h = (fabsf(x) < 0.0009765625f) ? (_Float16)0.f : (_Float16)x;
    const float hf = (float)h;
    hi   = h;
    lo64 = (_Float16)((x - hf) * 64.f);
    hi64 = (_Float16)(hf * 0.015625f);
}

// ================= prep: wT64 + f64-normalized codebooks + f16-split planes =================
__global__ void vq_prep(const float* __restrict__ w_in_a, const float* __restrict__ w_in_b,
                        const float* __restrict__ cb_a,  const float* __restrict__ cb_b,
                        double* __restrict__ wT64,
                        double* __restrict__ cbn64A, double* __restrict__ cbn64B,
                        f16x8* __restrict__ carr, int* __restrict__ cnt) {
    int id = blockIdx.x * 256 + threadIdx.x;
    if (id == 0) *cnt = 0;
    if (id < 16384) {
        int i = id >> 4, o = id & 15;
        float w = (o < 8) ? w_in_a[o * ND + i] : w_in_b[(o - 8) * ND + i];
        wT64[id] = (double)w;
    } else if (id < 16384 + 2 * CSZ) {
        int e = id - 16384;
        int book = e >> 12, j = e & (CSZ - 1);
        const float* src = (book ? cb_b : cb_a) + (size_t)j * CDIM;
        double* d64 = (book ? cbn64B : cbn64A) + (size_t)j * CDIM;
        double c[CDIM]; double n2 = 0.0;
#pragma unroll
        for (int k = 0; k < CDIM; ++k) { c[k] = (double)src[k]; n2 = fma(c[k], c[k], n2); }
        double den = fmax(sqrt(n2), 1e-12);
        f16x8 p0, p1, p2;
#pragma unroll
        for (int k = 0; k < CDIM; ++k) {
            double v = c[k] / den;
            d64[k] = v;
            _Float16 hi, lo64, hi64;
            split16((float)v, hi, lo64, hi64);
            p0[k] = hi; p1[k] = hi64; p2[k] = lo64;   // plane1 = chi/64, plane2 = clo*64
        }
        const size_t base = (size_t)(book * 3) * CSZ + j;
        carr[base]           = p0;
        carr[base + CSZ]     = p1;
        carr[base + 2 * CSZ] = p2;
    }
}

// ================= A: f64 projection + normalize + f16-split enc; 512 blocks x 512 =================
__global__ void __launch_bounds__(512, 4)
vq_proj(const float* __restrict__ z,
        const float* __restrict__ b_in_a, const float* __restrict__ b_in_b,
        const double* __restrict__ wT64,
        double* __restrict__ za64, f16x8* __restrict__ earr,
        float* __restrict__ out) {
    const int tid  = threadIdx.x;
    const int lane = tid & 63;
    const int wave = __builtin_amdgcn_readfirstlane(tid >> 6);  // 0..7
    const int blk  = blockIdx.x;
    const int b    = blk >> 6;
    const int t    = ((blk & 63) << 6) + lane;
    const int f    = (blk << 6) + lane;

    __shared__ double red[8][64][9];

    double acc[16];
#pragma unroll
    for (int k = 0; k < 16; ++k) acc[k] = 0.0;

    const float* zp = z + ((size_t)b * ND) * NT + t;
    const int i0 = wave * 128;
#pragma unroll 4
    for (int ii = 0; ii < 128; ++ii) {
        const int i = i0 + ii;
        const double zd = (double)zp[(size_t)i * NT];
        const double* wr = wT64 + (size_t)i * 16;               // uniform -> s_load
#pragma unroll
        for (int k = 0; k < 16; ++k) acc[k] = fma(wr[k], zd, acc[k]);
    }

    double za16[16];
#pragma unroll
    for (int r = 0; r < 2; ++r) {
#pragma unroll
        for (int k = 0; k < 8; ++k) red[wave][lane][k] = acc[8 * r + k];
        __syncthreads();
        if (wave == 0) {
#pragma unroll
            for (int k = 0; k < 8; ++k) {
                double s = red[0][lane][k];
#pragma unroll
                for (int w = 1; w < 8; ++w) s += red[w][lane][k];
                za16[8 * r + k] = s;
            }
        }
        __syncthreads();
    }
    if (wave != 0) return;

#pragma unroll
    for (int k = 0; k < 8; ++k) { za16[k] += (double)b_in_a[k]; za16[8 + k] += (double)b_in_b[k]; }

    // latent output (f32)
#pragma unroll
    for (int k = 0; k < 16; ++k)
        out[LAT_OFF + ((size_t)b * 16 + k) * NT + t] = (float)za16[k];

    // store za64 (rescue + losses)
    double* zf = za64 + (size_t)f * 16;
#pragma unroll
    for (int k = 0; k < 16; ++k) zf[k] = za16[k];

    // normalize f64 -> f16-split slots [f][book][slot]: s0=ehi, s1=elo*64, s2=ehi/64
    double n2a = 0.0, n2b = 0.0;
#pragma unroll
    for (int k = 0; k < 8; ++k) { n2a = fma(za16[k], za16[k], n2a); n2b = fma(za16[8+k], za16[8+k], n2b); }
    const double ia_ = 1.0 / fmax(sqrt(n2a), 1e-12);
    const double ib_ = 1.0 / fmax(sqrt(n2b), 1e-12);
#pragma unroll
    for (int book = 0; book < 2; ++book) {
        const double inv = book ? ib_ : ia_;
        f16x8 s0, s1, s2;
#pragma unroll
        for (int k = 0; k < 8; ++k) {
            const float e32 = (float)(za16[book * 8 + k] * inv);
            _Float16 hi, lo64, hi64;
            split16(e32, hi, lo64, hi64);
            s0[k] = hi; s1[k] = lo64; s2[k] = hi64;
        }
        const size_t base = (size_t)f * 6 + book * 3;
        earr[base]     = s0;
        earr[base + 1] = s1;
        earr[base + 2] = s2;
    }
}

// ================= B: 32x32 MFMA scan; 512 blocks x 256 thr =================
// wave = (framegroup fg = wave>>1) x (book = wave&1); 32 frames/wave, full codebook sweep.
__global__ void __launch_bounds__(256, 2)
vq_scan32(const f16x8* __restrict__ carr, const f16x8* __restrict__ earr,
          int* __restrict__ idxAB, int* __restrict__ list, int* __restrict__ cnt) {
    __shared__ f16x8 lds[6 * 512];                              // 48 KB: [book][plane][512 e]
    __shared__ int sIB[2][32];
    __shared__ int sNB[2][32];

    const int tid  = threadIdx.x;
    const int lane = tid & 63;
    const int wave = __builtin_amdgcn_readfirstlane(tid >> 6);  // 0..3
    const int book = wave & 1;
    const int fg   = wave >> 1;
    const int h    = lane >> 5;                                 // k-half
    const int c32  = lane & 31;                                 // frame-local col / entry row
    const int f    = blockIdx.x * 64 + fg * 32 + c32;

    // e slots in regs (B operand + epilogue)
    const f16x8 s0 = earr[(size_t)f * 6 + book * 3];
    const f16x8 s1 = earr[(size_t)f * 6 + book * 3 + 1];
    const f16x8 s2 = earr[(size_t)f * 6 + book * 3 + 2];
    f16x8 fz;
#pragma unroll
    for (int j = 0; j < 8; ++j) fz[j] = (_Float16)0.f;
    const f16x8 bf1 = h ? s1 : s0;                              // k0-7: ehi | k8-15: elo*64
    const f16x8 bf2 = h ? fz : s2;                              // k0-7: ehi/64 | k8-15: 0

    float b1 = -1e30f, b2 = -1e30f;
    int   bt = 0;

    const f16x8* pa1 = lds + (book * 3 + h) * 512;              // A k-half plane (chi | chi/64)
    const f16x8* pa2 = lds + (book * 3 + 2) * 512;              // clo*64 plane

    for (int ch = 0; ch < 8; ++ch) {
        __syncthreads();
#pragma unroll
        for (int it = 0; it < 12; ++it) {                       // stage 3072 f16x8 = 48 KB
            const int idx = it * 256 + tid;
            const int pp = idx >> 9, e = idx & 511;
            lds[pp * 512 + e] = carr[(size_t)pp * CSZ + (ch << 9) + e];
        }
        __syncthreads();
#pragma unroll 4
        for (int t = 0; t < 16; ++t) {                          // 16 tiles of 32 entries
            const f16x8 af1 = pa1[(t << 5) + c32];
            const f16x8 af2 = pa2[(t << 5) + c32];
            f32x16 z16 = {};
            f32x16 acc = __builtin_amdgcn_mfma_f32_32x32x16_f16(af1, bf1, z16, 0, 0, 0);
            acc = __builtin_amdgcn_mfma_f32_32x32x16_f16(af2, bf2, acc, 0, 0, 0);
            // tile max (value only)
            float m0 = fmaxf(fmaxf(acc[0], acc[1]), fmaxf(acc[2], acc[3]));
            float m1 = fmaxf(fmaxf(acc[4], acc[5]), fmaxf(acc[6], acc[7]));
            float m2 = fmaxf(fmaxf(acc[8], acc[9]), fmaxf(acc[10], acc[11]));
            float m3 = fmaxf(fmaxf(acc[12], acc[13]), fmaxf(acc[14], acc[15]));
            const float tv = fmaxf(fmaxf(m0, m1), fmaxf(m2, m3));
            const bool gt = tv > b1;                            // strict >: first tile wins ties
            b2 = fmaxf(b2, gt ? b1 : tv);
            b1 = gt ? tv : b1;
            bt = gt ? (ch * 16 + t) : bt;
        }
    }

    // ---- epilogue: recompute winning tile's 16 candidate rows in f32 (exact top-2 within tile) ----
    const f16x8* cap = carr + (size_t)(book * 3) * CSZ;
    float v1 = -1e30f, v2 = b2;                                 // v2 seeded with cross-tile 2nd
    int ei = 0;
#pragma unroll
    for (int r = 0; r < 16; ++r) {                              // ascending row within this lane's half
        const int row = (r & 3) + 8 * (r >> 2) + 4 * h;
        const int ent = bt * 32 + row;
        const f16x8 p0 = cap[ent];
        const f16x8 p1 = cap[CSZ + ent];
        const f16x8 p2 = cap[2 * CSZ + ent];
        float sr = 0.f;
#pragma unroll
        for (int j = 0; j < 8; ++j) {
            sr += (float)p0[j] * (float)s0[j];
            sr += (float)p1[j] * (float)s1[j];
            sr += (float)p2[j] * (float)s2[j];
        }
        const bool gt = sr > v1;
        v2 = fmaxf(v2, gt ? v1 : sr);
        v1 = gt ? sr : v1;
        ei = gt ? ent : ei;
    }
    // merge k-halves (interleaved rows): entry-id tie-break
    {
        const float o1 = __shfl_xor(v1, 32);
        const int   oe = __shfl_xor(ei, 32);
        const float o2 = __shfl_xor(v2, 32);
        const float mn = fminf(v1, o1);
        v2 = fmaxf(fmaxf(v2, o2), mn);
        const bool tk = (o1 > v1) || (o1 == v1 && oe < ei);
        v1 = tk ? o1 : v1;
        ei = tk ? oe : ei;
    }
    const bool needy = (v1 - v2) < TAU;

    if (lane < 32 && book == 1) { sIB[fg][c32] = ei; sNB[fg][c32] = needy ? 1 : 0; }
    __syncthreads();
    if (lane < 32 && book == 0) {
        const int ib = sIB[fg][c32];
        const int nB = sNB[fg][c32];
        idxAB[f] = (ei << 12) | ib;
        const int flags = (needy ? 1 : 0) | (nB << 1);
        if (flags) { const int p = atomicAdd(cnt, 1); list[p] = f | (flags << 16); }
    }
}

// ================= C: exact f64 rescue, one wave per needy frame =================
__global__ void __launch_bounds__(256, 4)
vq_rescue(const int* __restrict__ list, const int* __restrict__ cnt,
          const double* __restrict__ za64,
          const double* __restrict__ cbn64A, const double* __restrict__ cbn64B,
          int* __restrict__ idxAB) {
    const int lane = threadIdx.x & 63;
    const int wv   = (blockIdx.x << 2) + (threadIdx.x >> 6);
    const int n = *cnt;
    for (int it = wv; it < n; it += 1024) {
        const int v = list[it];
        const int fr = v & 0xFFFF;
        const bool nA = (v >> 16) & 1, nB = (v >> 17) & 1;
        const double* zr = za64 + (size_t)fr * 16;               // uniform -> s_load
        double zra[16];
#pragma unroll
        for (int k = 0; k < 16; ++k) zra[k] = zr[k];
        double n2a = 0.0, n2b = 0.0;
#pragma unroll
        for (int k = 0; k < 8; ++k) { n2a = fma(zra[k], zra[k], n2a); n2b = fma(zra[8+k], zra[8+k], n2b); }
        const double ja_ = 1.0 / fmax(sqrt(n2a), 1e-12);
        const double jb_ = 1.0 / fmax(sqrt(n2b), 1e-12);

        double bva = -1e300, bvb = -1e300; int ba = 0, bb = 0;
        if (nA) {
            double ea[8];
#pragma unroll
            for (int k = 0; k < 8; ++k) ea[k] = zra[k] * ja_;
            for (int e = lane; e < CSZ; e += 64) {
                const double* ra = cbn64A + (size_t)e * 8;
                double sA = 0.0;
#pragma unroll
                for (int k = 0; k < 8; ++k) sA = fma(ea[k], ra[k], sA);
                if (sA > bva) { bva = sA; ba = e; }
            }
        }
        if (nB) {
            double eb[8];
#pragma unroll
            for (int k = 0; k < 8; ++k) eb[k] = zra[8 + k] * jb_;
            for (int e = lane; e < CSZ; e += 64) {
                const double* rb = cbn64B + (size_t)e * 8;
                double sB = 0.0;
#pragma unroll
                for (int k = 0; k < 8; ++k) sB = fma(eb[k], rb[k], sB);
                if (sB > bvb) { bvb = sB; bb = e; }
            }
        }
#pragma unroll
        for (int off = 32; off > 0; off >>= 1) {
            double ov = __shfl_xor(bva, off); int oi = __shfl_xor(ba, off);
            if (ov > bva || (ov == bva && oi < ba)) { bva = ov; ba = oi; }
            ov = __shfl_xor(bvb, off); oi = __shfl_xor(bb, off);
            if (ov > bvb || (ov == bvb && oi < bb)) { bvb = ov; bb = oi; }
        }
        if (lane == 0) {
            const int old = idxAB[fr];
            const int ia2 = nA ? ba : (old >> 12);
            const int ib2 = nB ? bb : (old & 4095);
            idxAB[fr] = (ia2 << 12) | ib2;
        }
    }
}

// ================= D: streaming out-projection + (ct==0) idx/loss; 2048 blocks x 256 =================
__global__ void __launch_bounds__(256, 4)
vq_store(const int* __restrict__ idxAB, const double* __restrict__ za64,
         const float* __restrict__ cb_a, const float* __restrict__ cb_b,
         const float* __restrict__ w_out_a, const float* __restrict__ b_out_a,
         const float* __restrict__ w_out_b, const float* __restrict__ b_out_b,
         float* __restrict__ out, double* __restrict__ part) {
    const int tid  = threadIdx.x;
    const int lane = tid & 63;
    const int wave = __builtin_amdgcn_readfirstlane(tid >> 6);   // 0..3
    const int blk  = blockIdx.x;
    const int b    = blk >> 8;
    const int rem  = blk & 255;
    const int tt   = rem >> 4;                                   // 16 t-tiles of 256
    const int ct   = rem & 15;                                   // 16 c-tiles of 64
    const int t0   = (tt << 8) + (lane << 2);
    const int f0   = (b << 12) + t0;

    const bool bookb = (ct >= 8);
    const float* wO = bookb ? w_out_b : w_out_a;
    const float* bO = bookb ? b_out_b : b_out_a;
    const float* cbp = bookb ? cb_b : cb_a;

    const int4 codes = *(const int4*)(idxAB + f0);
    float qv[4][8];
    {
        const int cd[4] = {codes.x, codes.y, codes.z, codes.w};
#pragma unroll
        for (int j = 0; j < 4; ++j) {
            const int idx = bookb ? (cd[j] & 4095) : (cd[j] >> 12);
            const float4 q0 = *(const float4*)(cbp + (size_t)idx * CDIM);
            const float4 q1 = *(const float4*)(cbp + (size_t)idx * CDIM + 4);
            qv[j][0]=q0.x; qv[j][1]=q0.y; qv[j][2]=q0.z; qv[j][3]=q0.w;
            qv[j][4]=q1.x; qv[j][5]=q1.y; qv[j][6]=q1.z; qv[j][7]=q1.w;
        }
    }

    const int cl0 = ((ct & 7) << 6) + (wave << 4);
#pragma unroll 4
    for (int cc = 0; cc < 16; ++cc) {
        const int cl = cl0 + cc;
        const float* wr = wO + (size_t)cl * 8;                   // uniform -> s_load
        const float bias = bO[cl];
        float4 o = make_float4(bias, bias, bias, bias);
#pragma unroll
        for (int k = 0; k < 8; ++k) {
            o.x = fmaf(wr[k], qv[0][k], o.x);
            o.y = fmaf(wr[k], qv[1][k], o.y);
            o.z = fmaf(wr[k], qv[2][k], o.z);
            o.w = fmaf(wr[k], qv[3][k], o.w);
        }
        const int c = (bookb ? 512 : 0) + cl;
        *(float4*)(out + ((size_t)b * ND + c) * NT + t0) = o;
    }

    // ---- ct==0 blocks: idx output + deterministic loss partial for their 256 frames ----
    if (ct == 0) {
        const int fL = (b << 12) + (tt << 8) + tid;
        const int code = idxAB[fL];
        const int iA = code >> 12, iB = code & 4095;
        out[IDX_OFF + (size_t)fL] = (float)code;                 // < 2^24: exact in f32

        const float4 qa0 = *(const float4*)(cb_a + (size_t)iA * CDIM);
        const float4 qa1 = *(const float4*)(cb_a + (size_t)iA * CDIM + 4);
        const float4 qb0 = *(const float4*)(cb_b + (size_t)iB * CDIM);
        const float4 qb1 = *(const float4*)(cb_b + (size_t)iB * CDIM + 4);
        const float zaq[8] = {qa0.x, qa0.y, qa0.z, qa0.w, qa1.x, qa1.y, qa1.z, qa1.w};
        const float zbq[8] = {qb0.x, qb0.y, qb0.z, qb0.w, qb1.x, qb1.y, qb1.z, qb1.w};

        const double* zp = za64 + (size_t)fL * 16;
        double s = 0.0;
#pragma unroll
        for (int k = 0; k < 8; ++k) {
            const double d0 = zp[k]     - (double)zaq[k]; s = fma(d0, d0, s);
            const double d1 = zp[8 + k] - (double)zbq[k]; s = fma(d1, d1, s);
        }
        __shared__ double sred[256];
        sred[tid] = s;
        __syncthreads();
#pragma unroll
        for (int off = 128; off > 0; off >>= 1) {                // fixed tree: deterministic
            if (tid < off) sred[tid] += sred[tid + off];
            __syncthreads();
        }
        if (tid == 0) part[(b << 4) + tt] = sred[0];
    }
}

__global__ void vq_finalize(const double* __restrict__ part, float* __restrict__ out) {
    const int b = threadIdx.x;
    if (b < NB) {
        double s = 0.0;
        for (int j = 0; j < 16; ++j) s += part[b * 16 + j];      // fixed order: deterministic
        const float v = (float)(s * (1.0 / 32768.0));
        out[CL_OFF + b]  = v;
        out[CBL_OFF + b] = v;
    }
}

// ================= fallback monolith (round-1 proven, if ws too small) =================
__global__ void __launch_bounds__(256, 2)
vq_mono(const float* __restrict__ z,
        const float* __restrict__ w_in_a, const float* __restrict__ b_in_a,
        const float* __restrict__ w_in_b, const float* __restrict__ b_in_b,
        const float* __restrict__ w_out_a, const float* __restrict__ b_out_a,
        const float* __restrict__ w_out_b, const float* __restrict__ b_out_b,
        const float* __restrict__ cb_a, const float* __restrict__ cb_b,
        float* __restrict__ out, double* __restrict__ part) {
    const int tid  = threadIdx.x;
    const int lane = tid & 63;
    const int wave = __builtin_amdgcn_readfirstlane(tid >> 6);
    const int blk  = blockIdx.x;
    const int b    = blk >> 6;
    const int t    = ((blk & 63) << 6) + lane;

    __shared__ double red[4][64][9];
    __shared__ double sBest[2][4][64];
    __shared__ int    sIdx[2][4][64];

    double acc[16];
#pragma unroll
    for (int k = 0; k < 16; ++k) acc[k] = 0.0;
    const float* zp = z + ((size_t)b * ND) * NT + t;
    const int i0 = wave * 256;
#pragma unroll 2
    for (int ii = 0; ii < 256; ++ii) {
        const int i = i0 + ii;
        const double zd = (double)zp[(size_t)i * NT];
#pragma unroll
        for (int o = 0; o < 8; ++o) {
            acc[o]     = fma((double)w_in_a[o * ND + i], zd, acc[o]);
            acc[8 + o] = fma((double)w_in_b[o * ND + i], zd, acc[8 + o]);
        }
    }
    double za[16];
#pragma unroll
    for (int r = 0; r < 2; ++r) {
#pragma unroll
        for (int k = 0; k < 8; ++k) red[wave][lane][k] = acc[8 * r + k];
        __syncthreads();
#pragma unroll
        for (int k = 0; k < 8; ++k)
            za[8*r+k] = ((red[0][lane][k] + red[1][lane][k]) + red[2][lane][k]) + red[3][lane][k];
        __syncthreads();
    }
#pragma unroll
    for (int k = 0; k < 8; ++k) { za[k] += (double)b_in_a[k]; za[8 + k] += (double)b_in_b[k]; }

    if (wave == 0) {
#pragma unroll
        for (int k = 0; k < 16; ++k)
            out[LAT_OFF + ((size_t)b * 16 + k) * NT + t] = (float)za[k];
    }

    double ea[8], eb[8];
    {
        double n2 = 0.0;
#pragma unroll
        for (int k = 0; k < 8; ++k) n2 = fma(za[k], za[k], n2);
        double inv = 1.0 / fmax(sqrt(n2), 1e-12);
#pragma unroll
        for (int k = 0; k < 8; ++k) ea[k] = za[k] * inv;
    }
    {
        double n2 = 0.0;
#pragma unroll
        for (int k = 0; k < 8; ++k) n2 = fma(za[8 + k], za[8 + k], n2);
        double inv = 1.0 / fmax(sqrt(n2), 1e-12);
#pragma unroll
        for (int k = 0; k < 8; ++k) eb[k] = za[8 + k] * inv;
    }

    double bestA = -1e300, bestB = -1e300;
    int ibA = 0, ibB = 0;
    const int j0 = wave << 10;
    for (int jj = 0; jj < 1024; ++jj) {
        const int j = j0 + jj;
        const float* ra = cb_a + (size_t)j * CDIM;
        const float* rb = cb_b + (size_t)j * CDIM;
        double na = 0.0, nb = 0.0, sA = 0.0, sB = 0.0;
#pragma unroll
        for (int k = 0; k < 8; ++k) {
            double av = (double)ra[k], bv2 = (double)rb[k];
            na = fma(av, av, na); nb = fma(bv2, bv2, nb);
            sA = fma(ea[k], av, sA); sB = fma(eb[k], bv2, sB);
        }
        sA /= fmax(sqrt(na), 1e-12);
        sB /= fmax(sqrt(nb), 1e-12);
        if (sA > bestA) { bestA = sA; ibA = j; }
        if (sB > bestB) { bestB = sB; ibB = j; }
    }
    sBest[0][wave][lane] = bestA; sIdx[0][wave][lane] = ibA;
    sBest[1][wave][lane] = bestB; sIdx[1][wave][lane] = ibB;
    __syncthreads();

    double bA = sBest[0][0][lane]; int iA = sIdx[0][0][lane];
    double bB = sBest[1][0][lane]; int iB = sIdx[1][0][lane];
#pragma unroll
    for (int w2 = 1; w2 < 4; ++w2) {
        double d = sBest[0][w2][lane]; int j2 = sIdx[0][w2][lane];
        if (d > bA) { bA = d; iA = j2; }
        d = sBest[1][w2][lane]; j2 = sIdx[1][w2][lane];
        if (d > bB) { bB = d; iB = j2; }
    }

    float4 qa0 = *(const float4*)(cb_a + (size_t)iA * CDIM);
    float4 qa1 = *(const float4*)(cb_a + (size_t)iA * CDIM + 4);
    float4 qb0 = *(const float4*)(cb_b + (size_t)iB * CDIM);
    float4 qb1 = *(const float4*)(cb_b + (size_t)iB * CDIM + 4);
    float zaq[8] = {qa0.x, qa0.y, qa0.z, qa0.w, qa1.x, qa1.y, qa1.z, qa1.w};
    float zbq[8] = {qb0.x, qb0.y, qb0.z, qb0.w, qb1.x, qb1.y, qb1.z, qb1.w};

    if (wave == 0) {
        out[IDX_OFF + (size_t)b * NT + t] = (float)(iA * CSZ + iB);
        double s = 0.0;
#pragma unroll
        for (int k = 0; k < 8; ++k) {
            double d0 = za[k]     - (double)zaq[k]; s = fma(d0, d0, s);
            double d1 = za[8 + k] - (double)zbq[k]; s = fma(d1, d1, s);
        }
#pragma unroll
        for (int off = 32; off > 0; off >>= 1) s += __shfl_down(s, off);
        if (lane == 0) part[blk] = s;
    }

    const int c0 = wave << 7;
    const size_t obase = ((size_t)b * ND) * NT + t;
    for (int cc = 0; cc < 128; ++cc) {
        const int c = c0 + cc;
        const float* wa = w_out_a + (size_t)c * CDIM;
        const float* wb = w_out_b + (size_t)c * CDIM;
        float sa = b_out_a[c], sb = b_out_b[c];
#pragma unroll
        for (int k = 0; k < 8; ++k) { sa = fmaf(wa[k], zaq[k], sa); sb = fmaf(wb[k], zbq[k], sb); }
        out[obase + (size_t)c * NT]         = sa;
        out[obase + (size_t)(512 + c) * NT] = sb;
    }
}

__global__ void vq_finalize64(const double* __restrict__ part, float* __restrict__ out) {
    const int b = threadIdx.x;
    if (b < NB) {
        double s = 0.0;
        for (int j = 0; j < 64; ++j) s += part[(size_t)b * 64 + j];
        const float v = (float)(s * (1.0 / 32768.0));
        out[CL_OFF + b]  = v;
        out[CBL_OFF + b] = v;
    }
}

extern "C" void kernel_launch(void* const* d_in, const int* in_sizes, int n_in,
                              void* d_out, int out_size, void* d_ws, size_t ws_size,
                              hipStream_t stream) {
    const float* z       = (const float*)d_in[0];
    const float* w_in_a  = (const float*)d_in[1];
    const float* b_in_a  = (const float*)d_in[2];
    const float* w_in_b  = (const float*)d_in[3];
    const float* b_in_b  = (const float*)d_in[4];
    const float* w_out_a = (const float*)d_in[5];
    const float* b_out_a = (const float*)d_in[6];
    const float* w_out_b = (const float*)d_in[7];
    const float* b_out_b = (const float*)d_in[8];
    const float* cb_a    = (const float*)d_in[9];
    const float* cb_b    = (const float*)d_in[10];
    float* out = (float*)d_out;
    char* ws = (char*)d_ws;

    if (ws_size >= WS_NEED) {
        double* wT64   = (double*)(ws + WT64_B);
        double* cbn64A = (double*)(ws + CBN64A_B);
        double* cbn64B = (double*)(ws + CBN64B_B);
        f16x8*  carr   = (f16x8*) (ws + CARR_B);
        f16x8*  earr   = (f16x8*) (ws + EARR_B);
        double* za64   = (double*)(ws + ZA64_B);
        int*    idxAB  = (int*)   (ws + IDXW_B);
        int*    list   = (int*)   (ws + LIST_B);
        int*    cnt    = (int*)   (ws + CNT_B);
        double* part   = (double*)(ws + PART_B);

        vq_prep<<<96, 256, 0, stream>>>(w_in_a, w_in_b, cb_a, cb_b,
                                        wT64, cbn64A, cbn64B, carr, cnt);
        vq_proj<<<512, 512, 0, stream>>>(z, b_in_a, b_in_b, wT64, za64, earr, out);
        vq_scan32<<<512, 256, 0, stream>>>(carr, earr, idxAB, list, cnt);
        vq_rescue<<<256, 256, 0, stream>>>(list, cnt, za64, cbn64A, cbn64B, idxAB);
        vq_store<<<2048, 256, 0, stream>>>(idxAB, za64, cb_a, cb_b,
                                           w_out_a, b_out_a, w_out_b, b_out_b, out, part);
        vq_finalize<<<1, 64, 0, stream>>>(part, out);
    } else {
        double* part = (double*)ws;
        vq_mono<<<512, 256, 0, stream>>>(z, w_in_a, b_in_a, w_in_b, b_in_b,
                                         w_out_a, b_out_a, w_out_b, b_out_b,
                                         cb_a, cb_b, out, part);
        vq_finalize64<<<1, 64, 0, stream>>>(part, out);
    }
}